// Round 1
// baseline (2039.118 us; speedup 1.0000x reference)
//
#include <hip/hip_runtime.h>
#include <hip/hip_bf16.h>

// ChebNet: N=100000 nodes, E=3.2M edges, K=4, 128 -> 128(relu) -> 64 -> log_softmax
// Strategy: Clenshaw evaluation  sum_k T_k(L) x @ W_k  ==  Clenshaw(L, y_k) with
// y_k = x @ W_k  (polynomial in L commutes with channel-space matmul). This puts
// layer-2 propagation in 64-ch space (halves gather traffic vs the naive recurrence).

#define NN 100000
#define NE 3200000

// ---------------------------------------------------------------- degree / weights
__global__ void k_deg(const int* __restrict__ row, int* __restrict__ deg) {
    int e = blockIdx.x * blockDim.x + threadIdx.x;
    if (e < NE) atomicAdd(&deg[row[e]], 1);
}

__global__ void k_dis(const int* __restrict__ deg, float* __restrict__ dis) {
    int i = blockIdx.x * blockDim.x + threadIdx.x;
    if (i < NN) {
        int d = deg[i];
        dis[i] = (d > 0) ? rsqrtf((float)d) : 0.0f;
    }
}

// ---------------------------------------------------------------- 3-phase exclusive scan (row_ptr)
// chunks of 1024 elements per block (256 threads x 4)
__global__ void k_scan1(const int* __restrict__ deg, int* __restrict__ bsum) {
    __shared__ int sm[256];
    int t = threadIdx.x, b = blockIdx.x;
    int base = b * 1024 + t * 4;
    int s = 0;
    if (base + 3 < NN) {
        int4 q = *(const int4*)(deg + base);
        s = q.x + q.y + q.z + q.w;
    } else {
        for (int j = 0; j < 4; ++j) { int i = base + j; if (i < NN) s += deg[i]; }
    }
    sm[t] = s; __syncthreads();
    for (int st = 128; st > 0; st >>= 1) {
        if (t < st) sm[t] += sm[t + st];
        __syncthreads();
    }
    if (t == 0) bsum[b] = sm[0];
}

__global__ void k_scan2(int* __restrict__ bsum, int nb) {
    __shared__ int sm[128];
    int t = threadIdx.x;
    int v = (t < nb) ? bsum[t] : 0;
    sm[t] = v; __syncthreads();
    for (int st = 1; st < 128; st <<= 1) {
        int a = (t >= st) ? sm[t - st] : 0;
        __syncthreads();
        sm[t] += a;
        __syncthreads();
    }
    if (t < nb) bsum[t] = (t == 0) ? 0 : sm[t - 1];  // exclusive
}

__global__ void k_scan3(const int* __restrict__ deg, const int* __restrict__ bsum,
                        int* __restrict__ row_ptr) {
    __shared__ int sm[256];
    int t = threadIdx.x, b = blockIdx.x;
    int base = b * 1024 + t * 4;
    int v0 = 0, v1 = 0, v2 = 0, v3 = 0;
    if (base + 3 < NN) {
        int4 q = *(const int4*)(deg + base);
        v0 = q.x; v1 = q.y; v2 = q.z; v3 = q.w;
    } else {
        if (base     < NN) v0 = deg[base];
        if (base + 1 < NN) v1 = deg[base + 1];
        if (base + 2 < NN) v2 = deg[base + 2];
        if (base + 3 < NN) v3 = deg[base + 3];
    }
    int ts = v0 + v1 + v2 + v3;
    sm[t] = ts; __syncthreads();
    for (int st = 1; st < 256; st <<= 1) {
        int a = (t >= st) ? sm[t - st] : 0;
        __syncthreads();
        sm[t] += a;
        __syncthreads();
    }
    int ex = ((t == 0) ? 0 : sm[t - 1]) + bsum[b];
    if (base     < NN) row_ptr[base]     = ex;
    if (base + 1 < NN) row_ptr[base + 1] = ex + v0;
    if (base + 2 < NN) row_ptr[base + 2] = ex + v0 + v1;
    if (base + 3 < NN) row_ptr[base + 3] = ex + v0 + v1 + v2;
    if (b == 0 && t == 0) row_ptr[NN] = NE;  // total is exactly NE (all rows in [0,NN))
}

// ---------------------------------------------------------------- CSR fill (counting sort)
__global__ void k_fill(const int* __restrict__ row, const int* __restrict__ col,
                       const float* __restrict__ dis, int* __restrict__ cursor,
                       int* __restrict__ csr_col, float* __restrict__ csr_w) {
    int e = blockIdx.x * blockDim.x + threadIdx.x;
    if (e < NE) {
        int r = row[e], c = col[e];
        int p = atomicAdd(&cursor[r], 1);
        csr_col[p] = c;
        csr_w[p] = -dis[r] * dis[c];
    }
}

// ---------------------------------------------------------------- GEMM  Y[k] = X @ W[k]
// X: [NN,128] row-major. W: [4,128,C]. Y: [4,NN,C]. blockIdx.y = k.
// 64 rows/block, thread = (C/4 col-threads) x (256/(C/4) row-groups), 4 cols x RPT rows each.
template <int C>
__global__ __launch_bounds__(256) void k_gemm(const float* __restrict__ X,
                                              const float* __restrict__ W,
                                              float* __restrict__ Y) {
    __shared__ float xs[64 * 128];
    const int t = threadIdx.x;
    const int row0 = blockIdx.x * 64;
    const float* __restrict__ Wk = W + (size_t)blockIdx.y * 128 * C;
    float* __restrict__ Yk = Y + (size_t)blockIdx.y * (size_t)NN * C;

#pragma unroll
    for (int i = 0; i < 8; ++i) {
        int f = (t + i * 256) * 4;           // flat float index in 64x128 tile
        int r = f >> 7, cx = f & 127;
        int gr = row0 + r;
        float4 v = make_float4(0.f, 0.f, 0.f, 0.f);
        if (gr < NN) v = *(const float4*)(X + (size_t)gr * 128 + cx);
        *(float4*)(xs + f) = v;
    }
    __syncthreads();

    constexpr int COLT = C / 4;       // col-threads
    constexpr int RT = 256 / COLT;    // row-thread groups
    constexpr int RPT = 64 / RT;      // rows per thread
    const int ct = t % COLT, rt = t / COLT;
    const int col = ct * 4;

    float acc[RPT][4] = {};
    for (int k4 = 0; k4 < 128; k4 += 4) {
        float4 w0 = *(const float4*)(Wk + (size_t)(k4 + 0) * C + col);
        float4 w1 = *(const float4*)(Wk + (size_t)(k4 + 1) * C + col);
        float4 w2 = *(const float4*)(Wk + (size_t)(k4 + 2) * C + col);
        float4 w3 = *(const float4*)(Wk + (size_t)(k4 + 3) * C + col);
#pragma unroll
        for (int j = 0; j < RPT; ++j) {
            float4 xv = *(const float4*)(xs + (rt * RPT + j) * 128 + k4);
            acc[j][0] += xv.x * w0.x + xv.y * w1.x + xv.z * w2.x + xv.w * w3.x;
            acc[j][1] += xv.x * w0.y + xv.y * w1.y + xv.z * w2.y + xv.w * w3.y;
            acc[j][2] += xv.x * w0.z + xv.y * w1.z + xv.z * w2.z + xv.w * w3.z;
            acc[j][3] += xv.x * w0.w + xv.y * w1.w + xv.z * w2.w + xv.w * w3.w;
        }
    }
#pragma unroll
    for (int j = 0; j < RPT; ++j) {
        int gr = row0 + rt * RPT + j;
        if (gr < NN)
            *(float4*)(Yk + (size_t)gr * C + col) =
                make_float4(acc[j][0], acc[j][1], acc[j][2], acc[j][3]);
    }
}

// ---------------------------------------------------------------- propagation (SpMM row-wave)
// dst[r][:] = scale * sum_e w_e * src[col_e][:]  + A[r][:] + betaB*B[r][:] (+bias, relu)
// one wave per row; C=128 -> float2/lane, C=64 -> float/lane.
template <int C>
__global__ __launch_bounds__(256) void k_prop(const int* __restrict__ rp,
                                              const int* __restrict__ cc,
                                              const float* __restrict__ cw,
                                              const float* __restrict__ src,
                                              const float* __restrict__ A,
                                              const float* __restrict__ B,
                                              const float* __restrict__ bias,
                                              float scale, float betaB, int do_relu,
                                              float* __restrict__ dst) {
    const int wid = threadIdx.x >> 6;
    const int lane = threadIdx.x & 63;
    const int r = blockIdx.x * 4 + wid;
    if (r >= NN) return;
    const int e0 = rp[r], e1 = rp[r + 1];

    if (C == 128) {
        float2 acc = make_float2(0.f, 0.f);
        for (int eb = e0; eb < e1; eb += 64) {
            int n = e1 - eb; if (n > 64) n = 64;
            int ee = eb + lane;
            int cl = (ee < e1) ? cc[ee] : 0;
            float wl = (ee < e1) ? cw[ee] : 0.f;
            for (int i = 0; i < n; ++i) {
                int c = __shfl(cl, i);
                float wv = __shfl(wl, i);
                float2 v = *(const float2*)(src + (size_t)c * 128 + lane * 2);
                acc.x += wv * v.x;
                acc.y += wv * v.y;
            }
        }
        size_t o = (size_t)r * 128 + lane * 2;
        float2 res;
        res.x = scale * acc.x + A[o];
        res.y = scale * acc.y + A[o + 1];
        if (B) { res.x += betaB * B[o]; res.y += betaB * B[o + 1]; }
        if (bias) { res.x += bias[lane * 2]; res.y += bias[lane * 2 + 1]; }
        if (do_relu) { res.x = fmaxf(res.x, 0.f); res.y = fmaxf(res.y, 0.f); }
        *(float2*)(dst + o) = res;
    } else {
        float acc = 0.f;
        for (int eb = e0; eb < e1; eb += 64) {
            int n = e1 - eb; if (n > 64) n = 64;
            int ee = eb + lane;
            int cl = (ee < e1) ? cc[ee] : 0;
            float wl = (ee < e1) ? cw[ee] : 0.f;
            for (int i = 0; i < n; ++i) {
                int c = __shfl(cl, i);
                float wv = __shfl(wl, i);
                acc += wv * src[(size_t)c * 64 + lane];
            }
        }
        size_t o = (size_t)r * 64 + lane;
        float res = scale * acc + A[o];
        if (B) res += betaB * B[o];
        if (bias) res += bias[lane];
        if (do_relu) res = fmaxf(res, 0.f);
        dst[o] = res;
    }
}

// ---------------------------------------------------------------- fused bias + log_softmax (64 ch)
__global__ __launch_bounds__(256) void k_lsm(float* __restrict__ out,
                                             const float* __restrict__ bias) {
    const int wid = threadIdx.x >> 6;
    const int lane = threadIdx.x & 63;
    const int r = blockIdx.x * 4 + wid;
    if (r >= NN) return;
    size_t o = (size_t)r * 64 + lane;
    float v = out[o] + bias[lane];
    float m = v;
    for (int s = 32; s > 0; s >>= 1) m = fmaxf(m, __shfl_xor(m, s));
    float ex = expf(v - m);
    float sum = ex;
    for (int s = 32; s > 0; s >>= 1) sum += __shfl_xor(sum, s);
    out[o] = v - m - logf(sum);
}

// ---------------------------------------------------------------- host launch
extern "C" void kernel_launch(void* const* d_in, const int* in_sizes, int n_in,
                              void* d_out, int out_size, void* d_ws, size_t ws_size,
                              hipStream_t stream) {
    const float* x  = (const float*)d_in[0];   // [NN,128]
    const float* W1 = (const float*)d_in[1];   // [4,128,128]
    const float* b1 = (const float*)d_in[2];   // [128]
    const float* W2 = (const float*)d_in[3];   // [4,128,64]
    const float* b2 = (const float*)d_in[4];   // [64]
    const int* ei   = (const int*)d_in[5];     // [2,NE] int
    const int* erow = ei;
    const int* ecol = ei + NE;
    float* out = (float*)d_out;                // [NN,64]

    // workspace layout (256B aligned)
    char* w = (char*)d_ws;
    size_t off = 0;
    auto alloc = [&](size_t bytes) {
        size_t o = off;
        off += (bytes + 255) & ~(size_t)255;
        return o;
    };
    int*   deg     = (int*)(w + alloc((size_t)NN * 4));
    float* dis     = (float*)(w + alloc((size_t)NN * 4));
    int*   row_ptr = (int*)(w + alloc((size_t)(NN + 1) * 4));
    int*   cursor  = (int*)(w + alloc((size_t)NN * 4));
    int*   bsum    = (int*)(w + alloc(256 * 4));
    int*   csr_col = (int*)(w + alloc((size_t)NE * 4));
    float* csr_w   = (float*)(w + alloc((size_t)NE * 4));
    float* Y       = (float*)(w + alloc((size_t)4 * NN * 128 * 4));  // Y0..Y3
    float* Y0 = Y;
    float* Y1 = Y + (size_t)1 * NN * 128;
    float* Y2 = Y + (size_t)2 * NN * 128;
    float* Y3 = Y + (size_t)3 * NN * 128;
    // layer-2 z buffers reuse Y1..Y2 region (4 * NN * 64 == 2 * NN * 128)
    float* Z0 = Y1;
    float* Z1 = Y1 + (size_t)1 * NN * 64;
    float* Z2 = Y1 + (size_t)2 * NN * 64;
    float* Z3 = Y1 + (size_t)3 * NN * 64;

    const int nbE = (NE + 255) / 256;       // 12500
    const int nbN = (NN + 255) / 256;       // 391
    const int nbS = (NN + 1023) / 1024;     // 98
    const int pb  = (NN + 3) / 4;           // 25000 (4 rows/block wave kernels)
    const dim3 gg((NN + 63) / 64, 4);       // gemm grid, y = k

    // ---- graph weights -> CSR
    hipMemsetAsync(deg, 0, (size_t)NN * 4, stream);
    k_deg<<<nbE, 256, 0, stream>>>(erow, deg);
    k_dis<<<nbN, 256, 0, stream>>>(deg, dis);
    k_scan1<<<nbS, 256, 0, stream>>>(deg, bsum);
    k_scan2<<<1, 128, 0, stream>>>(bsum, nbS);
    k_scan3<<<nbS, 256, 0, stream>>>(deg, bsum, row_ptr);
    hipMemcpyAsync(cursor, row_ptr, (size_t)NN * 4, hipMemcpyDeviceToDevice, stream);
    k_fill<<<nbE, 256, 0, stream>>>(erow, ecol, dis, cursor, csr_col, csr_w);

    // ---- layer 1: y_k = x @ W1[k]; Clenshaw; bias+relu fused into last prop
    k_gemm<128><<<gg, 256, 0, stream>>>(x, W1, Y);
    // b2' = y2 + 2 P y3            (in-place into Y2)
    k_prop<128><<<pb, 256, 0, stream>>>(row_ptr, csr_col, csr_w, Y3, Y2, nullptr,
                                        nullptr, 2.f, 0.f, 0, Y2);
    // b1' = y1 + 2 P b2' - y3      (in-place into Y1)
    k_prop<128><<<pb, 256, 0, stream>>>(row_ptr, csr_col, csr_w, Y2, Y1, Y3,
                                        nullptr, 2.f, -1.f, 0, Y1);
    // h = relu(y0 + P b1' - b2' + bias1)   (in-place into Y0)
    k_prop<128><<<pb, 256, 0, stream>>>(row_ptr, csr_col, csr_w, Y1, Y0, Y2,
                                        b1, 1.f, -1.f, 1, Y0);

    // ---- layer 2: z_k = h @ W2[k]; Clenshaw in 64-ch space
    k_gemm<64><<<gg, 256, 0, stream>>>(Y0, W2, Z0);
    k_prop<64><<<pb, 256, 0, stream>>>(row_ptr, csr_col, csr_w, Z3, Z2, nullptr,
                                       nullptr, 2.f, 0.f, 0, Z2);
    k_prop<64><<<pb, 256, 0, stream>>>(row_ptr, csr_col, csr_w, Z2, Z1, Z3,
                                       nullptr, 2.f, -1.f, 0, Z1);
    k_prop<64><<<pb, 256, 0, stream>>>(row_ptr, csr_col, csr_w, Z1, Z0, Z2,
                                       nullptr, 1.f, -1.f, 0, out);

    // ---- bias2 + log_softmax
    k_lsm<<<pb, 256, 0, stream>>>(out, b2);
}

// Round 2
// 1801.336 us; speedup vs baseline: 1.1320x; 1.1320x over previous
//
#include <hip/hip_runtime.h>
#include <hip/hip_bf16.h>
#include <hip/hip_fp16.h>

// ChebNet: N=100000 nodes, E=3.2M edges, K=4, 128 -> 128(relu) -> 64 -> log_softmax
// Clenshaw form: sum_k T_k(L) x @ W_k == Clenshaw(L, y_k), y_k = x @ W_k.
// R2: all propagated operands stored fp16 (gather bytes halve; L2-miss BW is the
// binding resource per R1 counters), fp32 accumulation everywhere. CSR metadata
// packed int2 (col, weight bits).

#define NN 100000
#define NE 3200000

// ---------------------------------------------------------------- degree / weights
__global__ void k_deg(const int* __restrict__ row, int* __restrict__ deg) {
    int e = blockIdx.x * blockDim.x + threadIdx.x;
    if (e < NE) atomicAdd(&deg[row[e]], 1);
}

__global__ void k_dis(const int* __restrict__ deg, float* __restrict__ dis) {
    int i = blockIdx.x * blockDim.x + threadIdx.x;
    if (i < NN) {
        int d = deg[i];
        dis[i] = (d > 0) ? rsqrtf((float)d) : 0.0f;
    }
}

// ---------------------------------------------------------------- 3-phase exclusive scan (row_ptr)
__global__ void k_scan1(const int* __restrict__ deg, int* __restrict__ bsum) {
    __shared__ int sm[256];
    int t = threadIdx.x, b = blockIdx.x;
    int base = b * 1024 + t * 4;
    int s = 0;
    if (base + 3 < NN) {
        int4 q = *(const int4*)(deg + base);
        s = q.x + q.y + q.z + q.w;
    } else {
        for (int j = 0; j < 4; ++j) { int i = base + j; if (i < NN) s += deg[i]; }
    }
    sm[t] = s; __syncthreads();
    for (int st = 128; st > 0; st >>= 1) {
        if (t < st) sm[t] += sm[t + st];
        __syncthreads();
    }
    if (t == 0) bsum[b] = sm[0];
}

__global__ void k_scan2(int* __restrict__ bsum, int nb) {
    __shared__ int sm[128];
    int t = threadIdx.x;
    int v = (t < nb) ? bsum[t] : 0;
    sm[t] = v; __syncthreads();
    for (int st = 1; st < 128; st <<= 1) {
        int a = (t >= st) ? sm[t - st] : 0;
        __syncthreads();
        sm[t] += a;
        __syncthreads();
    }
    if (t < nb) bsum[t] = (t == 0) ? 0 : sm[t - 1];  // exclusive
}

__global__ void k_scan3(const int* __restrict__ deg, const int* __restrict__ bsum,
                        int* __restrict__ row_ptr) {
    __shared__ int sm[256];
    int t = threadIdx.x, b = blockIdx.x;
    int base = b * 1024 + t * 4;
    int v0 = 0, v1 = 0, v2 = 0, v3 = 0;
    if (base + 3 < NN) {
        int4 q = *(const int4*)(deg + base);
        v0 = q.x; v1 = q.y; v2 = q.z; v3 = q.w;
    } else {
        if (base     < NN) v0 = deg[base];
        if (base + 1 < NN) v1 = deg[base + 1];
        if (base + 2 < NN) v2 = deg[base + 2];
        if (base + 3 < NN) v3 = deg[base + 3];
    }
    int ts = v0 + v1 + v2 + v3;
    sm[t] = ts; __syncthreads();
    for (int st = 1; st < 256; st <<= 1) {
        int a = (t >= st) ? sm[t - st] : 0;
        __syncthreads();
        sm[t] += a;
        __syncthreads();
    }
    int ex = ((t == 0) ? 0 : sm[t - 1]) + bsum[b];
    if (base     < NN) row_ptr[base]     = ex;
    if (base + 1 < NN) row_ptr[base + 1] = ex + v0;
    if (base + 2 < NN) row_ptr[base + 2] = ex + v0 + v1;
    if (base + 3 < NN) row_ptr[base + 3] = ex + v0 + v1 + v2;
    if (b == 0 && t == 0) row_ptr[NN] = NE;
}

// ---------------------------------------------------------------- CSR fill (counting sort, packed)
__global__ void k_fill(const int* __restrict__ row, const int* __restrict__ col,
                       const float* __restrict__ dis, int* __restrict__ cursor,
                       int2* __restrict__ ed) {
    int e = blockIdx.x * blockDim.x + threadIdx.x;
    if (e < NE) {
        int r = row[e], c = col[e];
        int p = atomicAdd(&cursor[r], 1);
        ed[p] = make_int2(c, __float_as_int(-dis[r] * dis[c]));
    }
}

// ---------------------------------------------------------------- GEMM  Y[k] = X @ W[k]  (fp16 out)
__device__ inline float4 load4f(const float* p) { return *(const float4*)p; }
__device__ inline float4 load4f(const __half* p) {
    float2 a = __half22float2(*(const __half2*)p);
    float2 b = __half22float2(*(const __half2*)(p + 2));
    return make_float4(a.x, a.y, b.x, b.y);
}

template <int C, typename TX>
__global__ __launch_bounds__(256) void k_gemm(const TX* __restrict__ X,
                                              const float* __restrict__ W,
                                              __half* __restrict__ Y) {
    __shared__ float xs[64 * 128];
    const int t = threadIdx.x;
    const int row0 = blockIdx.x * 64;
    const float* __restrict__ Wk = W + (size_t)blockIdx.y * 128 * C;
    __half* __restrict__ Yk = Y + (size_t)blockIdx.y * (size_t)NN * C;

#pragma unroll
    for (int i = 0; i < 8; ++i) {
        int f = (t + i * 256) * 4;           // flat float index in 64x128 tile
        int r = f >> 7, cx = f & 127;
        int gr = row0 + r;
        float4 v = make_float4(0.f, 0.f, 0.f, 0.f);
        if (gr < NN) v = load4f(X + (size_t)gr * 128 + cx);
        *(float4*)(xs + f) = v;
    }
    __syncthreads();

    constexpr int COLT = C / 4;       // col-threads
    constexpr int RT = 256 / COLT;    // row-thread groups
    constexpr int RPT = 64 / RT;      // rows per thread
    const int ct = t % COLT, rt = t / COLT;
    const int col = ct * 4;

    float acc[RPT][4] = {};
    for (int k4 = 0; k4 < 128; k4 += 4) {
        float4 w0 = *(const float4*)(Wk + (size_t)(k4 + 0) * C + col);
        float4 w1 = *(const float4*)(Wk + (size_t)(k4 + 1) * C + col);
        float4 w2 = *(const float4*)(Wk + (size_t)(k4 + 2) * C + col);
        float4 w3 = *(const float4*)(Wk + (size_t)(k4 + 3) * C + col);
#pragma unroll
        for (int j = 0; j < RPT; ++j) {
            float4 xv = *(const float4*)(xs + (rt * RPT + j) * 128 + k4);
            acc[j][0] += xv.x * w0.x + xv.y * w1.x + xv.z * w2.x + xv.w * w3.x;
            acc[j][1] += xv.x * w0.y + xv.y * w1.y + xv.z * w2.y + xv.w * w3.y;
            acc[j][2] += xv.x * w0.z + xv.y * w1.z + xv.z * w2.z + xv.w * w3.z;
            acc[j][3] += xv.x * w0.w + xv.y * w1.w + xv.z * w2.w + xv.w * w3.w;
        }
    }
#pragma unroll
    for (int j = 0; j < RPT; ++j) {
        int gr = row0 + rt * RPT + j;
        if (gr < NN) {
            __half2* p = (__half2*)(Yk + (size_t)gr * C + col);
            p[0] = __float22half2_rn(make_float2(acc[j][0], acc[j][1]));
            p[1] = __float22half2_rn(make_float2(acc[j][2], acc[j][3]));
        }
    }
}

// ---------------------------------------------------------------- propagation (SpMM row-wave, fp16)
// dst[r][:] = scale * sum_e w_e * src[col_e][:] + A[r][:] + betaB*B[r][:] (+bias, relu)
template <int C>
__global__ __launch_bounds__(256) void k_prop(const int* __restrict__ rp,
                                              const int2* __restrict__ ed,
                                              const __half* __restrict__ src,
                                              const __half* __restrict__ A,
                                              const __half* __restrict__ B,
                                              const float* __restrict__ bias,
                                              float scale, float betaB, int do_relu,
                                              __half* __restrict__ dsth,
                                              float* __restrict__ dstf) {
    const int wid = threadIdx.x >> 6;
    const int lane = threadIdx.x & 63;
    const int r = blockIdx.x * 4 + wid;
    if (r >= NN) return;
    const int e0 = rp[r], e1 = rp[r + 1];

    if (C == 128) {
        float2 acc = make_float2(0.f, 0.f);
        for (int eb = e0; eb < e1; eb += 64) {
            int n = e1 - eb; if (n > 64) n = 64;
            int ee = eb + lane;
            int2 el = (ee < e1) ? ed[ee] : make_int2(0, 0);
            for (int i = 0; i < n; ++i) {
                int c = __shfl(el.x, i);
                float wv = __int_as_float(__shfl(el.y, i));
                float2 v = __half22float2(*(const __half2*)(src + (size_t)c * 128 + lane * 2));
                acc.x += wv * v.x;
                acc.y += wv * v.y;
            }
        }
        size_t o = (size_t)r * 128 + lane * 2;
        float2 av = __half22float2(*(const __half2*)(A + o));
        float2 res;
        res.x = scale * acc.x + av.x;
        res.y = scale * acc.y + av.y;
        if (B) {
            float2 bv = __half22float2(*(const __half2*)(B + o));
            res.x += betaB * bv.x; res.y += betaB * bv.y;
        }
        if (bias) { res.x += bias[lane * 2]; res.y += bias[lane * 2 + 1]; }
        if (do_relu) { res.x = fmaxf(res.x, 0.f); res.y = fmaxf(res.y, 0.f); }
        if (dsth) *(__half2*)(dsth + o) = __float22half2_rn(res);
        if (dstf) *(float2*)(dstf + o) = res;
    } else {
        float acc = 0.f;
        for (int eb = e0; eb < e1; eb += 64) {
            int n = e1 - eb; if (n > 64) n = 64;
            int ee = eb + lane;
            int2 el = (ee < e1) ? ed[ee] : make_int2(0, 0);
            for (int i = 0; i < n; ++i) {
                int c = __shfl(el.x, i);
                float wv = __int_as_float(__shfl(el.y, i));
                acc += wv * __half2float(src[(size_t)c * 64 + lane]);
            }
        }
        size_t o = (size_t)r * 64 + lane;
        float res = scale * acc + __half2float(A[o]);
        if (B) res += betaB * __half2float(B[o]);
        if (bias) res += bias[lane];
        if (do_relu) res = fmaxf(res, 0.f);
        if (dsth) dsth[o] = __float2half_rn(res);
        if (dstf) dstf[o] = res;
    }
}

// ---------------------------------------------------------------- fused bias + log_softmax (64 ch)
__global__ __launch_bounds__(256) void k_lsm(float* __restrict__ out,
                                             const float* __restrict__ bias) {
    const int wid = threadIdx.x >> 6;
    const int lane = threadIdx.x & 63;
    const int r = blockIdx.x * 4 + wid;
    if (r >= NN) return;
    size_t o = (size_t)r * 64 + lane;
    float v = out[o] + bias[lane];
    float m = v;
    for (int s = 32; s > 0; s >>= 1) m = fmaxf(m, __shfl_xor(m, s));
    float ex = expf(v - m);
    float sum = ex;
    for (int s = 32; s > 0; s >>= 1) sum += __shfl_xor(sum, s);
    out[o] = v - m - logf(sum);
}

// ---------------------------------------------------------------- host launch
extern "C" void kernel_launch(void* const* d_in, const int* in_sizes, int n_in,
                              void* d_out, int out_size, void* d_ws, size_t ws_size,
                              hipStream_t stream) {
    const float* x  = (const float*)d_in[0];   // [NN,128]
    const float* W1 = (const float*)d_in[1];   // [4,128,128]
    const float* b1 = (const float*)d_in[2];   // [128]
    const float* W2 = (const float*)d_in[3];   // [4,128,64]
    const float* b2 = (const float*)d_in[4];   // [64]
    const int* ei   = (const int*)d_in[5];     // [2,NE] int
    const int* erow = ei;
    const int* ecol = ei + NE;
    float* out = (float*)d_out;                // [NN,64]

    char* w = (char*)d_ws;
    size_t off = 0;
    auto alloc = [&](size_t bytes) {
        size_t o = off;
        off += (bytes + 255) & ~(size_t)255;
        return o;
    };
    int*   deg     = (int*)(w + alloc((size_t)NN * 4));
    float* dis     = (float*)(w + alloc((size_t)NN * 4));
    int*   row_ptr = (int*)(w + alloc((size_t)(NN + 1) * 4));
    int*   cursor  = (int*)(w + alloc((size_t)NN * 4));
    int*   bsum    = (int*)(w + alloc(256 * 4));
    int2*  ed      = (int2*)(w + alloc((size_t)NE * 8));
    __half* Y      = (__half*)(w + alloc((size_t)4 * NN * 128 * 2));  // Y0..Y3 fp16
    __half* Y0 = Y;
    __half* Y1 = Y + (size_t)1 * NN * 128;
    __half* Y2 = Y + (size_t)2 * NN * 128;
    __half* Y3 = Y + (size_t)3 * NN * 128;
    // layer-2 Z buffers reuse Y1..Y2 region (4 * NN * 64 == 2 * NN * 128 halves)
    __half* Z0 = Y1;
    __half* Z1 = Y1 + (size_t)1 * NN * 64;
    __half* Z2 = Y1 + (size_t)2 * NN * 64;
    __half* Z3 = Y1 + (size_t)3 * NN * 64;

    const int nbE = (NE + 255) / 256;       // 12500
    const int nbN = (NN + 255) / 256;       // 391
    const int nbS = (NN + 1023) / 1024;     // 98
    const int pb  = (NN + 3) / 4;           // 25000
    const dim3 gg((NN + 63) / 64, 4);       // gemm grid, y = k

    // ---- graph weights -> CSR
    hipMemsetAsync(deg, 0, (size_t)NN * 4, stream);
    k_deg<<<nbE, 256, 0, stream>>>(erow, deg);
    k_dis<<<nbN, 256, 0, stream>>>(deg, dis);
    k_scan1<<<nbS, 256, 0, stream>>>(deg, bsum);
    k_scan2<<<1, 128, 0, stream>>>(bsum, nbS);
    k_scan3<<<nbS, 256, 0, stream>>>(deg, bsum, row_ptr);
    hipMemcpyAsync(cursor, row_ptr, (size_t)NN * 4, hipMemcpyDeviceToDevice, stream);
    k_fill<<<nbE, 256, 0, stream>>>(erow, ecol, dis, cursor, ed);

    // ---- layer 1: y_k = x @ W1[k]; Clenshaw; bias+relu fused into last prop
    k_gemm<128, float><<<gg, 256, 0, stream>>>(x, W1, Y);
    // b2 = y2 + 2 P y3                 (in-place into Y2)
    k_prop<128><<<pb, 256, 0, stream>>>(row_ptr, ed, Y3, Y2, nullptr,
                                        nullptr, 2.f, 0.f, 0, Y2, nullptr);
    // b1 = y1 + 2 P b2 - y3            (in-place into Y1)
    k_prop<128><<<pb, 256, 0, stream>>>(row_ptr, ed, Y2, Y1, Y3,
                                        nullptr, 2.f, -1.f, 0, Y1, nullptr);
    // h = relu(y0 + P b1 - b2 + bias1) (in-place into Y0)
    k_prop<128><<<pb, 256, 0, stream>>>(row_ptr, ed, Y1, Y0, Y2,
                                        b1, 1.f, -1.f, 1, Y0, nullptr);

    // ---- layer 2: z_k = h @ W2[k]; Clenshaw in 64-ch space
    k_gemm<64, __half><<<gg, 256, 0, stream>>>(Y0, W2, Z0);
    k_prop<64><<<pb, 256, 0, stream>>>(row_ptr, ed, Z3, Z2, nullptr,
                                       nullptr, 2.f, 0.f, 0, Z2, nullptr);
    k_prop<64><<<pb, 256, 0, stream>>>(row_ptr, ed, Z2, Z1, Z3,
                                       nullptr, 2.f, -1.f, 0, Z1, nullptr);
    k_prop<64><<<pb, 256, 0, stream>>>(row_ptr, ed, Z1, Z0, Z2,
                                       nullptr, 1.f, -1.f, 0, nullptr, out);

    // ---- bias2 + log_softmax
    k_lsm<<<pb, 256, 0, stream>>>(out, b2);
}

// Round 3
// 1643.599 us; speedup vs baseline: 1.2406x; 1.0960x over previous
//
#include <hip/hip_runtime.h>
#include <hip/hip_bf16.h>
#include <hip/hip_fp16.h>

// ChebNet: N=100000 nodes, E=3.2M edges, K=4, 128 -> 128(relu) -> 64 -> log_softmax
// Clenshaw form: sum_k T_k(L) x @ W_k == Clenshaw(L, y_k), y_k = x @ W_k.
// R3: GEMMs on MFMA f16 (R2 showed k_gemm VALU-bound at 199us, MfmaUtil=0).
//     One fused GEMM per layer (N = 4*C), Wt pre-transposed [N][K] fp16.
//     bias2+log_softmax fused into final prop (wave holds a full 64-ch row).

#define NN 100000
#define NE 3200000

using half8 = __attribute__((ext_vector_type(8))) _Float16;
using floatx4 = __attribute__((ext_vector_type(4))) float;

// ---------------------------------------------------------------- degree / weights
__global__ void k_deg(const int* __restrict__ row, int* __restrict__ deg) {
    int e = blockIdx.x * blockDim.x + threadIdx.x;
    if (e < NE) atomicAdd(&deg[row[e]], 1);
}

__global__ void k_dis(const int* __restrict__ deg, float* __restrict__ dis) {
    int i = blockIdx.x * blockDim.x + threadIdx.x;
    if (i < NN) {
        int d = deg[i];
        dis[i] = (d > 0) ? rsqrtf((float)d) : 0.0f;
    }
}

// ---------------------------------------------------------------- 3-phase exclusive scan (row_ptr)
__global__ void k_scan1(const int* __restrict__ deg, int* __restrict__ bsum) {
    __shared__ int sm[256];
    int t = threadIdx.x, b = blockIdx.x;
    int base = b * 1024 + t * 4;
    int s = 0;
    if (base + 3 < NN) {
        int4 q = *(const int4*)(deg + base);
        s = q.x + q.y + q.z + q.w;
    } else {
        for (int j = 0; j < 4; ++j) { int i = base + j; if (i < NN) s += deg[i]; }
    }
    sm[t] = s; __syncthreads();
    for (int st = 128; st > 0; st >>= 1) {
        if (t < st) sm[t] += sm[t + st];
        __syncthreads();
    }
    if (t == 0) bsum[b] = sm[0];
}

__global__ void k_scan2(int* __restrict__ bsum, int nb) {
    __shared__ int sm[128];
    int t = threadIdx.x;
    int v = (t < nb) ? bsum[t] : 0;
    sm[t] = v; __syncthreads();
    for (int st = 1; st < 128; st <<= 1) {
        int a = (t >= st) ? sm[t - st] : 0;
        __syncthreads();
        sm[t] += a;
        __syncthreads();
    }
    if (t < nb) bsum[t] = (t == 0) ? 0 : sm[t - 1];  // exclusive
}

__global__ void k_scan3(const int* __restrict__ deg, const int* __restrict__ bsum,
                        int* __restrict__ row_ptr) {
    __shared__ int sm[256];
    int t = threadIdx.x, b = blockIdx.x;
    int base = b * 1024 + t * 4;
    int v0 = 0, v1 = 0, v2 = 0, v3 = 0;
    if (base + 3 < NN) {
        int4 q = *(const int4*)(deg + base);
        v0 = q.x; v1 = q.y; v2 = q.z; v3 = q.w;
    } else {
        if (base     < NN) v0 = deg[base];
        if (base + 1 < NN) v1 = deg[base + 1];
        if (base + 2 < NN) v2 = deg[base + 2];
        if (base + 3 < NN) v3 = deg[base + 3];
    }
    int ts = v0 + v1 + v2 + v3;
    sm[t] = ts; __syncthreads();
    for (int st = 1; st < 256; st <<= 1) {
        int a = (t >= st) ? sm[t - st] : 0;
        __syncthreads();
        sm[t] += a;
        __syncthreads();
    }
    int ex = ((t == 0) ? 0 : sm[t - 1]) + bsum[b];
    if (base     < NN) row_ptr[base]     = ex;
    if (base + 1 < NN) row_ptr[base + 1] = ex + v0;
    if (base + 2 < NN) row_ptr[base + 2] = ex + v0 + v1;
    if (base + 3 < NN) row_ptr[base + 3] = ex + v0 + v1 + v2;
    if (b == 0 && t == 0) row_ptr[NN] = NE;
}

// ---------------------------------------------------------------- CSR fill (counting sort, packed)
__global__ void k_fill(const int* __restrict__ row, const int* __restrict__ col,
                       const float* __restrict__ dis, int* __restrict__ cursor,
                       int2* __restrict__ ed) {
    int e = blockIdx.x * blockDim.x + threadIdx.x;
    if (e < NE) {
        int r = row[e], c = col[e];
        int p = atomicAdd(&cursor[r], 1);
        ed[p] = make_int2(c, __float_as_int(-dis[r] * dis[c]));
    }
}

// ---------------------------------------------------------------- W transpose -> fp16 [N][K]
// Wt1[n][k] = W1[n>>7][k][n&127]  (n<512);  Wt2[n][k] = W2[n>>6][k][n&63]  (n<256)
__global__ void k_wt(const float* __restrict__ W1, const float* __restrict__ W2,
                     __half* __restrict__ Wt1, __half* __restrict__ Wt2) {
    int tid = blockIdx.x * 256 + threadIdx.x;
    if (tid < 512 * 128) {
        int n = tid >> 7, k = tid & 127;
        Wt1[tid] = __float2half_rn(W1[(((n >> 7) * 128) + k) * 128 + (n & 127)]);
    } else {
        int t2 = tid - 512 * 128;
        if (t2 < 256 * 128) {
            int n = t2 >> 7, k = t2 & 127;
            Wt2[t2] = __float2half_rn(W2[(((n >> 6) * 128) + k) * 64 + (n & 63)]);
        }
    }
}

// ---------------------------------------------------------------- MFMA GEMM  Y = X @ Wt^T
// X: [NN,128] (fp32 or fp16). Wt: [N][128] fp16 (pre-transposed). Output split into
// per-k buffers of OUTC channels: Y + (nglobal/OUTC)*NN*OUTC + node*OUTC + nglobal%OUTC.
// Block: 256 thr = 4 waves, tile 128 rows x 128 cols, whole K=128 resident in LDS.
template <int OUTC, typename TX>
__global__ __launch_bounds__(256) void k_mm(const TX* __restrict__ X,
                                            const __half* __restrict__ Wt,
                                            __half* __restrict__ Y) {
    __shared__ __half As[128 * 136];   // +8 pad breaks b128 bank aliasing
    const int t = threadIdx.x;
    const int lane = t & 63;
    const int w = t >> 6;
    const int r0 = blockIdx.x * 128;
    const int n0 = blockIdx.y * 128;

    // ---- stage A tile (128 rows x 128 k) as fp16
    if constexpr (sizeof(TX) == 4) {
#pragma unroll
        for (int i = 0; i < 16; ++i) {
            int v = t + i * 256;            // float4 index over 128x32
            int row = v >> 5, c4 = v & 31;
            float4 xv = make_float4(0.f, 0.f, 0.f, 0.f);
            if (r0 + row < NN) xv = *(const float4*)((const float*)X + (size_t)(r0 + row) * 128 + c4 * 4);
            __half2* p = (__half2*)(As + row * 136 + c4 * 4);
            p[0] = __float22half2_rn(make_float2(xv.x, xv.y));
            p[1] = __float22half2_rn(make_float2(xv.z, xv.w));
        }
    } else {
#pragma unroll
        for (int i = 0; i < 8; ++i) {
            int v = t + i * 256;            // 8-half chunk over 128x16
            int row = v >> 4, c8 = v & 15;
            uint4 xv = make_uint4(0, 0, 0, 0);
            if (r0 + row < NN) xv = *(const uint4*)((const __half*)X + (size_t)(r0 + row) * 128 + c8 * 8);
            *(uint4*)(As + row * 136 + c8 * 8) = xv;
        }
    }
    __syncthreads();

    const int m = lane & 15, quad = lane >> 4;
    floatx4 acc[2][8] = {};
    const __half* wb = Wt + (size_t)(n0 + m) * 128 + quad * 8;
    const __half* ab = As + (w * 32 + m) * 136 + quad * 8;

#pragma unroll
    for (int ks = 0; ks < 4; ++ks) {
        half8 a0 = *(const half8*)(ab + ks * 32);
        half8 a1 = *(const half8*)(ab + 16 * 136 + ks * 32);
#pragma unroll
        for (int nt = 0; nt < 8; ++nt) {
            half8 b = *(const half8*)(wb + (size_t)nt * 16 * 128 + ks * 32);
            acc[0][nt] = __builtin_amdgcn_mfma_f32_16x16x32_f16(a0, b, acc[0][nt], 0, 0, 0);
            acc[1][nt] = __builtin_amdgcn_mfma_f32_16x16x32_f16(a1, b, acc[1][nt], 0, 0, 0);
        }
    }

    __syncthreads();   // A reads done; reuse LDS for C tile
#pragma unroll
    for (int mt = 0; mt < 2; ++mt)
#pragma unroll
        for (int nt = 0; nt < 8; ++nt)
#pragma unroll
            for (int rg = 0; rg < 4; ++rg)
                As[(w * 32 + mt * 16 + quad * 4 + rg) * 136 + nt * 16 + m] =
                    __float2half_rn(acc[mt][nt][rg]);
    __syncthreads();

#pragma unroll
    for (int i = 0; i < 8; ++i) {
        int v = t + i * 256;
        int row = v >> 4, c8 = v & 15;
        int node = r0 + row;
        if (node < NN) {
            uint4 val = *(const uint4*)(As + row * 136 + c8 * 8);
            int ng = n0 + c8 * 8;
            __half* dst;
            if (OUTC == 128) dst = Y + ((size_t)(ng >> 7) * NN + node) * 128 + (ng & 127);
            else             dst = Y + ((size_t)(ng >> 6) * NN + node) * 64 + (ng & 63);
            *(uint4*)dst = val;
        }
    }
}

// ---------------------------------------------------------------- propagation (SpMM row-wave, fp16)
// dst[r][:] = scale * sum_e w_e * src[col_e][:] + A[r][:] + betaB*B[r][:] (+bias, relu, lsm)
template <int C>
__global__ __launch_bounds__(256) void k_prop(const int* __restrict__ rp,
                                              const int2* __restrict__ ed,
                                              const __half* __restrict__ src,
                                              const __half* __restrict__ A,
                                              const __half* __restrict__ B,
                                              const float* __restrict__ bias,
                                              float scale, float betaB, int do_relu,
                                              int do_lsm,
                                              __half* __restrict__ dsth,
                                              float* __restrict__ dstf) {
    const int wid = threadIdx.x >> 6;
    const int lane = threadIdx.x & 63;
    const int r = blockIdx.x * 4 + wid;
    if (r >= NN) return;
    const int e0 = rp[r], e1 = rp[r + 1];

    if (C == 128) {
        float2 acc = make_float2(0.f, 0.f);
        for (int eb = e0; eb < e1; eb += 64) {
            int n = e1 - eb; if (n > 64) n = 64;
            int ee = eb + lane;
            int2 el = (ee < e1) ? ed[ee] : make_int2(0, 0);
            for (int i = 0; i < n; ++i) {
                int c = __shfl(el.x, i);
                float wv = __int_as_float(__shfl(el.y, i));
                float2 v = __half22float2(*(const __half2*)(src + (size_t)c * 128 + lane * 2));
                acc.x += wv * v.x;
                acc.y += wv * v.y;
            }
        }
        size_t o = (size_t)r * 128 + lane * 2;
        float2 av = __half22float2(*(const __half2*)(A + o));
        float2 res;
        res.x = scale * acc.x + av.x;
        res.y = scale * acc.y + av.y;
        if (B) {
            float2 bv = __half22float2(*(const __half2*)(B + o));
            res.x += betaB * bv.x; res.y += betaB * bv.y;
        }
        if (bias) { res.x += bias[lane * 2]; res.y += bias[lane * 2 + 1]; }
        if (do_relu) { res.x = fmaxf(res.x, 0.f); res.y = fmaxf(res.y, 0.f); }
        if (dsth) *(__half2*)(dsth + o) = __float22half2_rn(res);
        if (dstf) *(float2*)(dstf + o) = res;
    } else {
        float acc = 0.f;
        for (int eb = e0; eb < e1; eb += 64) {
            int n = e1 - eb; if (n > 64) n = 64;
            int ee = eb + lane;
            int2 el = (ee < e1) ? ed[ee] : make_int2(0, 0);
            for (int i = 0; i < n; ++i) {
                int c = __shfl(el.x, i);
                float wv = __int_as_float(__shfl(el.y, i));
                acc += wv * __half2float(src[(size_t)c * 64 + lane]);
            }
        }
        size_t o = (size_t)r * 64 + lane;
        float res = scale * acc + __half2float(A[o]);
        if (B) res += betaB * __half2float(B[o]);
        if (bias) res += bias[lane];
        if (do_relu) res = fmaxf(res, 0.f);
        if (do_lsm) {
            float mx = res;
            for (int s = 32; s > 0; s >>= 1) mx = fmaxf(mx, __shfl_xor(mx, s));
            float ex = expf(res - mx);
            float sum = ex;
            for (int s = 32; s > 0; s >>= 1) sum += __shfl_xor(sum, s);
            res = res - mx - logf(sum);
        }
        if (dsth) dsth[o] = __float2half_rn(res);
        if (dstf) dstf[o] = res;
    }
}

// ---------------------------------------------------------------- host launch
extern "C" void kernel_launch(void* const* d_in, const int* in_sizes, int n_in,
                              void* d_out, int out_size, void* d_ws, size_t ws_size,
                              hipStream_t stream) {
    const float* x  = (const float*)d_in[0];   // [NN,128]
    const float* W1 = (const float*)d_in[1];   // [4,128,128]
    const float* b1 = (const float*)d_in[2];   // [128]
    const float* W2 = (const float*)d_in[3];   // [4,128,64]
    const float* b2 = (const float*)d_in[4];   // [64]
    const int* ei   = (const int*)d_in[5];     // [2,NE] int
    const int* erow = ei;
    const int* ecol = ei + NE;
    float* out = (float*)d_out;                // [NN,64]

    char* w = (char*)d_ws;
    size_t off = 0;
    auto alloc = [&](size_t bytes) {
        size_t o = off;
        off += (bytes + 255) & ~(size_t)255;
        return o;
    };
    int*   deg     = (int*)(w + alloc((size_t)NN * 4));
    float* dis     = (float*)(w + alloc((size_t)NN * 4));
    int*   row_ptr = (int*)(w + alloc((size_t)(NN + 1) * 4));
    int*   cursor  = (int*)(w + alloc((size_t)NN * 4));
    int*   bsum    = (int*)(w + alloc(256 * 4));
    __half* Wt1    = (__half*)(w + alloc((size_t)512 * 128 * 2));
    __half* Wt2    = (__half*)(w + alloc((size_t)256 * 128 * 2));
    int2*  ed      = (int2*)(w + alloc((size_t)NE * 8));
    __half* Y      = (__half*)(w + alloc((size_t)4 * NN * 128 * 2));  // Y0..Y3 fp16
    __half* Y0 = Y;
    __half* Y1 = Y + (size_t)1 * NN * 128;
    __half* Y2 = Y + (size_t)2 * NN * 128;
    __half* Y3 = Y + (size_t)3 * NN * 128;
    // layer-2 Z buffers reuse Y1..Y2 region (4 * NN * 64 == 2 * NN * 128 halves)
    __half* Z0 = Y1;
    __half* Z1 = Y1 + (size_t)1 * NN * 64;
    __half* Z2 = Y1 + (size_t)2 * NN * 64;
    __half* Z3 = Y1 + (size_t)3 * NN * 64;

    const int nbE = (NE + 255) / 256;       // 12500
    const int nbN = (NN + 255) / 256;       // 391
    const int nbS = (NN + 1023) / 1024;     // 98
    const int pb  = (NN + 3) / 4;           // 25000
    const dim3 g1((NN + 127) / 128, 4);     // layer-1 gemm: N=512
    const dim3 g2((NN + 127) / 128, 2);     // layer-2 gemm: N=256

    // ---- graph weights -> CSR (+ W transpose, independent)
    hipMemsetAsync(deg, 0, (size_t)NN * 4, stream);
    k_wt<<<384, 256, 0, stream>>>(W1, W2, Wt1, Wt2);
    k_deg<<<nbE, 256, 0, stream>>>(erow, deg);
    k_dis<<<nbN, 256, 0, stream>>>(deg, dis);
    k_scan1<<<nbS, 256, 0, stream>>>(deg, bsum);
    k_scan2<<<1, 128, 0, stream>>>(bsum, nbS);
    k_scan3<<<nbS, 256, 0, stream>>>(deg, bsum, row_ptr);
    hipMemcpyAsync(cursor, row_ptr, (size_t)NN * 4, hipMemcpyDeviceToDevice, stream);
    k_fill<<<nbE, 256, 0, stream>>>(erow, ecol, dis, cursor, ed);

    // ---- layer 1: y_k = x @ W1[k] (one MFMA gemm); Clenshaw; bias+relu in last prop
    k_mm<128, float><<<g1, 256, 0, stream>>>(x, Wt1, Y);
    // b2 = y2 + 2 P y3                 (in-place into Y2)
    k_prop<128><<<pb, 256, 0, stream>>>(row_ptr, ed, Y3, Y2, nullptr,
                                        nullptr, 2.f, 0.f, 0, 0, Y2, nullptr);
    // b1 = y1 + 2 P b2 - y3            (in-place into Y1)
    k_prop<128><<<pb, 256, 0, stream>>>(row_ptr, ed, Y2, Y1, Y3,
                                        nullptr, 2.f, -1.f, 0, 0, Y1, nullptr);
    // h = relu(y0 + P b1 - b2 + bias1) (in-place into Y0)
    k_prop<128><<<pb, 256, 0, stream>>>(row_ptr, ed, Y1, Y0, Y2,
                                        b1, 1.f, -1.f, 1, 0, Y0, nullptr);

    // ---- layer 2: z_k = h @ W2[k] (one MFMA gemm); Clenshaw in 64-ch space
    k_mm<64, __half><<<g2, 256, 0, stream>>>(Y0, Wt2, Z0);
    k_prop<64><<<pb, 256, 0, stream>>>(row_ptr, ed, Z3, Z2, nullptr,
                                       nullptr, 2.f, 0.f, 0, 0, Z2, nullptr);
    k_prop<64><<<pb, 256, 0, stream>>>(row_ptr, ed, Z2, Z1, Z3,
                                       nullptr, 2.f, -1.f, 0, 0, Z1, nullptr);
    // final: out = lsm(z0 + P b1 - b2 + bias2), fp32 straight to d_out
    k_prop<64><<<pb, 256, 0, stream>>>(row_ptr, ed, Z1, Z0, Z2,
                                       b2, 1.f, -1.f, 0, 1, nullptr, out);
}

// Round 4
// 1072.460 us; speedup vs baseline: 1.9013x; 1.5326x over previous
//
#include <hip/hip_runtime.h>
#include <hip/hip_bf16.h>
#include <hip/hip_fp16.h>

// ChebNet: N=100000 nodes, E=3.2M edges, K=4, 128 -> 128(relu) -> 64 -> log_softmax
// Clenshaw form: sum_k T_k(L) x @ W_k == Clenshaw(L, y_k), y_k = x @ W_k.
// R4: prop restructured for MLP — R3 counters showed latency-bound (no pipe >28%,
//     hbm 26%): multi-edge-per-wave gather (16B/lane), no shfl in hot loop,
//     x2 software pipeline, butterfly reduce once per row.

#define NN 100000
#define NE 3200000

using half8 = __attribute__((ext_vector_type(8))) _Float16;
using floatx4 = __attribute__((ext_vector_type(4))) float;

// ---------------------------------------------------------------- degree / weights
__global__ void k_deg(const int* __restrict__ row, int* __restrict__ deg) {
    int e = blockIdx.x * blockDim.x + threadIdx.x;
    if (e < NE) atomicAdd(&deg[row[e]], 1);
}

__global__ void k_dis(const int* __restrict__ deg, float* __restrict__ dis) {
    int i = blockIdx.x * blockDim.x + threadIdx.x;
    if (i < NN) {
        int d = deg[i];
        dis[i] = (d > 0) ? rsqrtf((float)d) : 0.0f;
    }
}

// ---------------------------------------------------------------- 3-phase exclusive scan (row_ptr)
__global__ void k_scan1(const int* __restrict__ deg, int* __restrict__ bsum) {
    __shared__ int sm[256];
    int t = threadIdx.x, b = blockIdx.x;
    int base = b * 1024 + t * 4;
    int s = 0;
    if (base + 3 < NN) {
        int4 q = *(const int4*)(deg + base);
        s = q.x + q.y + q.z + q.w;
    } else {
        for (int j = 0; j < 4; ++j) { int i = base + j; if (i < NN) s += deg[i]; }
    }
    sm[t] = s; __syncthreads();
    for (int st = 128; st > 0; st >>= 1) {
        if (t < st) sm[t] += sm[t + st];
        __syncthreads();
    }
    if (t == 0) bsum[b] = sm[0];
}

__global__ void k_scan2(int* __restrict__ bsum, int nb) {
    __shared__ int sm[128];
    int t = threadIdx.x;
    int v = (t < nb) ? bsum[t] : 0;
    sm[t] = v; __syncthreads();
    for (int st = 1; st < 128; st <<= 1) {
        int a = (t >= st) ? sm[t - st] : 0;
        __syncthreads();
        sm[t] += a;
        __syncthreads();
    }
    if (t < nb) bsum[t] = (t == 0) ? 0 : sm[t - 1];  // exclusive
}

__global__ void k_scan3(const int* __restrict__ deg, const int* __restrict__ bsum,
                        int* __restrict__ row_ptr) {
    __shared__ int sm[256];
    int t = threadIdx.x, b = blockIdx.x;
    int base = b * 1024 + t * 4;
    int v0 = 0, v1 = 0, v2 = 0, v3 = 0;
    if (base + 3 < NN) {
        int4 q = *(const int4*)(deg + base);
        v0 = q.x; v1 = q.y; v2 = q.z; v3 = q.w;
    } else {
        if (base     < NN) v0 = deg[base];
        if (base + 1 < NN) v1 = deg[base + 1];
        if (base + 2 < NN) v2 = deg[base + 2];
        if (base + 3 < NN) v3 = deg[base + 3];
    }
    int ts = v0 + v1 + v2 + v3;
    sm[t] = ts; __syncthreads();
    for (int st = 1; st < 256; st <<= 1) {
        int a = (t >= st) ? sm[t - st] : 0;
        __syncthreads();
        sm[t] += a;
        __syncthreads();
    }
    int ex = ((t == 0) ? 0 : sm[t - 1]) + bsum[b];
    if (base     < NN) row_ptr[base]     = ex;
    if (base + 1 < NN) row_ptr[base + 1] = ex + v0;
    if (base + 2 < NN) row_ptr[base + 2] = ex + v0 + v1;
    if (base + 3 < NN) row_ptr[base + 3] = ex + v0 + v1 + v2;
    if (b == 0 && t == 0) row_ptr[NN] = NE;
}

// ---------------------------------------------------------------- CSR fill (counting sort, packed)
__global__ void k_fill(const int* __restrict__ row, const int* __restrict__ col,
                       const float* __restrict__ dis, int* __restrict__ cursor,
                       int2* __restrict__ ed) {
    int e = blockIdx.x * blockDim.x + threadIdx.x;
    if (e < NE) {
        int r = row[e], c = col[e];
        int p = atomicAdd(&cursor[r], 1);
        ed[p] = make_int2(c, __float_as_int(-dis[r] * dis[c]));
    }
}

// ---------------------------------------------------------------- W transpose -> fp16 [N][K]
__global__ void k_wt(const float* __restrict__ W1, const float* __restrict__ W2,
                     __half* __restrict__ Wt1, __half* __restrict__ Wt2) {
    int tid = blockIdx.x * 256 + threadIdx.x;
    if (tid < 512 * 128) {
        int n = tid >> 7, k = tid & 127;
        Wt1[tid] = __float2half_rn(W1[(((n >> 7) * 128) + k) * 128 + (n & 127)]);
    } else {
        int t2 = tid - 512 * 128;
        if (t2 < 256 * 128) {
            int n = t2 >> 7, k = t2 & 127;
            Wt2[t2] = __float2half_rn(W2[(((n >> 6) * 128) + k) * 64 + (n & 63)]);
        }
    }
}

// ---------------------------------------------------------------- MFMA GEMM  Y = X @ Wt^T
template <int OUTC, typename TX>
__global__ __launch_bounds__(256) void k_mm(const TX* __restrict__ X,
                                            const __half* __restrict__ Wt,
                                            __half* __restrict__ Y) {
    __shared__ __half As[128 * 136];
    const int t = threadIdx.x;
    const int lane = t & 63;
    const int w = t >> 6;
    const int r0 = blockIdx.x * 128;
    const int n0 = blockIdx.y * 128;

    if constexpr (sizeof(TX) == 4) {
#pragma unroll
        for (int i = 0; i < 16; ++i) {
            int v = t + i * 256;
            int row = v >> 5, c4 = v & 31;
            float4 xv = make_float4(0.f, 0.f, 0.f, 0.f);
            if (r0 + row < NN) xv = *(const float4*)((const float*)X + (size_t)(r0 + row) * 128 + c4 * 4);
            __half2* p = (__half2*)(As + row * 136 + c4 * 4);
            p[0] = __float22half2_rn(make_float2(xv.x, xv.y));
            p[1] = __float22half2_rn(make_float2(xv.z, xv.w));
        }
    } else {
#pragma unroll
        for (int i = 0; i < 8; ++i) {
            int v = t + i * 256;
            int row = v >> 4, c8 = v & 15;
            uint4 xv = make_uint4(0, 0, 0, 0);
            if (r0 + row < NN) xv = *(const uint4*)((const __half*)X + (size_t)(r0 + row) * 128 + c8 * 8);
            *(uint4*)(As + row * 136 + c8 * 8) = xv;
        }
    }
    __syncthreads();

    const int m = lane & 15, quad = lane >> 4;
    floatx4 acc[2][8] = {};
    const __half* wb = Wt + (size_t)(n0 + m) * 128 + quad * 8;
    const __half* ab = As + (w * 32 + m) * 136 + quad * 8;

#pragma unroll
    for (int ks = 0; ks < 4; ++ks) {
        half8 a0 = *(const half8*)(ab + ks * 32);
        half8 a1 = *(const half8*)(ab + 16 * 136 + ks * 32);
#pragma unroll
        for (int nt = 0; nt < 8; ++nt) {
            half8 b = *(const half8*)(wb + (size_t)nt * 16 * 128 + ks * 32);
            acc[0][nt] = __builtin_amdgcn_mfma_f32_16x16x32_f16(a0, b, acc[0][nt], 0, 0, 0);
            acc[1][nt] = __builtin_amdgcn_mfma_f32_16x16x32_f16(a1, b, acc[1][nt], 0, 0, 0);
        }
    }

    __syncthreads();
#pragma unroll
    for (int mt = 0; mt < 2; ++mt)
#pragma unroll
        for (int nt = 0; nt < 8; ++nt)
#pragma unroll
            for (int rg = 0; rg < 4; ++rg)
                As[(w * 32 + mt * 16 + quad * 4 + rg) * 136 + nt * 16 + m] =
                    __float2half_rn(acc[mt][nt][rg]);
    __syncthreads();

#pragma unroll
    for (int i = 0; i < 8; ++i) {
        int v = t + i * 256;
        int row = v >> 4, c8 = v & 15;
        int node = r0 + row;
        if (node < NN) {
            uint4 val = *(const uint4*)(As + row * 136 + c8 * 8);
            int ng = n0 + c8 * 8;
            __half* dst;
            if (OUTC == 128) dst = Y + ((size_t)(ng >> 7) * NN + node) * 128 + (ng & 127);
            else             dst = Y + ((size_t)(ng >> 6) * NN + node) * 64 + (ng & 63);
            *(uint4*)dst = val;
        }
    }
}

// ---------------------------------------------------------------- propagation (SpMM, multi-edge wave)
// dst[r][:] = scale * sum_e w_e * src[col_e][:] + A[r][:] + betaB*B[r][:] (+bias, relu, lsm)
// wave = 1 row; EG edges in flight x LPE lanes x 8 half channels; no shfl in hot loop.
template <int C>
__global__ __launch_bounds__(256) void k_prop(const int* __restrict__ rp,
                                              const int2* __restrict__ ed,
                                              const __half* __restrict__ src,
                                              const __half* __restrict__ A,
                                              const __half* __restrict__ B,
                                              const float* __restrict__ bias,
                                              float scale, float betaB, int do_relu,
                                              int do_lsm,
                                              __half* __restrict__ dsth,
                                              float* __restrict__ dstf) {
    constexpr int LPE = C / 8;     // lanes per edge (half8 each)
    constexpr int EG = 64 / LPE;   // concurrent edges per wave
    const int wid = threadIdx.x >> 6;
    const int lane = threadIdx.x & 63;
    const int r = blockIdx.x * 4 + wid;
    if (r >= NN) return;
    const int e0 = rp[r], e1 = rp[r + 1];
    const int eg = lane / LPE, li = lane % LPE;

    float acc[8] = {};
    int e = e0 + eg;
    int2 el0 = (e < e1) ? ed[e] : make_int2(0, 0);
    int2 el1 = (e + EG < e1) ? ed[e + EG] : make_int2(0, 0);
    const int nit2 = (e1 - e0 + 2 * EG - 1) / (2 * EG);   // wave-uniform
    for (int it = 0; it < nit2; ++it) {
        half8 v0 = *(const half8*)(src + (size_t)el0.x * C + li * 8);
        half8 v1 = *(const half8*)(src + (size_t)el1.x * C + li * 8);
        int en0 = e + 2 * EG, en1 = e + 3 * EG;
        int2 p0 = (en0 < e1) ? ed[en0] : make_int2(0, 0);
        int2 p1 = (en1 < e1) ? ed[en1] : make_int2(0, 0);
        float w0 = __int_as_float(el0.y);
        float w1 = __int_as_float(el1.y);
#pragma unroll
        for (int j = 0; j < 8; ++j)
            acc[j] = fmaf(w0, (float)v0[j], fmaf(w1, (float)v1[j], acc[j]));
        e = en0; el0 = p0; el1 = p1;
    }

    // butterfly-reduce across edge groups (all lanes end with the row sum)
#pragma unroll
    for (int msk = LPE; msk < 64; msk <<= 1)
#pragma unroll
        for (int j = 0; j < 8; ++j)
            acc[j] += __shfl_xor(acc[j], msk);

    if (eg == 0) {
        size_t o = (size_t)r * C + li * 8;
        float res[8];
        half8 av = *(const half8*)(A + o);
#pragma unroll
        for (int j = 0; j < 8; ++j) res[j] = scale * acc[j] + (float)av[j];
        if (B) {
            half8 bv = *(const half8*)(B + o);
#pragma unroll
            for (int j = 0; j < 8; ++j) res[j] += betaB * (float)bv[j];
        }
        if (bias) {
            float4 b0 = *(const float4*)(bias + li * 8);
            float4 b1 = *(const float4*)(bias + li * 8 + 4);
            res[0] += b0.x; res[1] += b0.y; res[2] += b0.z; res[3] += b0.w;
            res[4] += b1.x; res[5] += b1.y; res[6] += b1.z; res[7] += b1.w;
        }
        if (do_relu)
#pragma unroll
            for (int j = 0; j < 8; ++j) res[j] = fmaxf(res[j], 0.f);
        if (do_lsm) {   // C==64: active lanes 0..7, xor masks stay inside the set
            float mx = res[0];
#pragma unroll
            for (int j = 1; j < 8; ++j) mx = fmaxf(mx, res[j]);
            for (int s = 1; s < LPE; s <<= 1) mx = fmaxf(mx, __shfl_xor(mx, s));
            float sum = 0.f;
#pragma unroll
            for (int j = 0; j < 8; ++j) sum += expf(res[j] - mx);
            for (int s = 1; s < LPE; s <<= 1) sum += __shfl_xor(sum, s);
            float lg = mx + logf(sum);
#pragma unroll
            for (int j = 0; j < 8; ++j) res[j] -= lg;
        }
        if (dsth) {
            half8 hv;
#pragma unroll
            for (int j = 0; j < 8; ++j) hv[j] = (_Float16)res[j];
            *(half8*)(dsth + o) = hv;
        }
        if (dstf) {
            *(float4*)(dstf + o) = make_float4(res[0], res[1], res[2], res[3]);
            *(float4*)(dstf + o + 4) = make_float4(res[4], res[5], res[6], res[7]);
        }
    }
}

// ---------------------------------------------------------------- host launch
extern "C" void kernel_launch(void* const* d_in, const int* in_sizes, int n_in,
                              void* d_out, int out_size, void* d_ws, size_t ws_size,
                              hipStream_t stream) {
    const float* x  = (const float*)d_in[0];   // [NN,128]
    const float* W1 = (const float*)d_in[1];   // [4,128,128]
    const float* b1 = (const float*)d_in[2];   // [128]
    const float* W2 = (const float*)d_in[3];   // [4,128,64]
    const float* b2 = (const float*)d_in[4];   // [64]
    const int* ei   = (const int*)d_in[5];     // [2,NE] int
    const int* erow = ei;
    const int* ecol = ei + NE;
    float* out = (float*)d_out;                // [NN,64]

    char* w = (char*)d_ws;
    size_t off = 0;
    auto alloc = [&](size_t bytes) {
        size_t o = off;
        off += (bytes + 255) & ~(size_t)255;
        return o;
    };
    int*   deg     = (int*)(w + alloc((size_t)NN * 4));
    float* dis     = (float*)(w + alloc((size_t)NN * 4));
    int*   row_ptr = (int*)(w + alloc((size_t)(NN + 1) * 4));
    int*   cursor  = (int*)(w + alloc((size_t)NN * 4));
    int*   bsum    = (int*)(w + alloc(256 * 4));
    __half* Wt1    = (__half*)(w + alloc((size_t)512 * 128 * 2));
    __half* Wt2    = (__half*)(w + alloc((size_t)256 * 128 * 2));
    int2*  ed      = (int2*)(w + alloc((size_t)NE * 8));
    __half* Y      = (__half*)(w + alloc((size_t)4 * NN * 128 * 2));  // Y0..Y3 fp16
    __half* Y0 = Y;
    __half* Y1 = Y + (size_t)1 * NN * 128;
    __half* Y2 = Y + (size_t)2 * NN * 128;
    __half* Y3 = Y + (size_t)3 * NN * 128;
    __half* Z0 = Y1;
    __half* Z1 = Y1 + (size_t)1 * NN * 64;
    __half* Z2 = Y1 + (size_t)2 * NN * 64;
    __half* Z3 = Y1 + (size_t)3 * NN * 64;

    const int nbE = (NE + 255) / 256;
    const int nbN = (NN + 255) / 256;
    const int nbS = (NN + 1023) / 1024;
    const int pb  = (NN + 3) / 4;
    const dim3 g1((NN + 127) / 128, 4);
    const dim3 g2((NN + 127) / 128, 2);

    // ---- graph weights -> CSR (+ W transpose, independent)
    hipMemsetAsync(deg, 0, (size_t)NN * 4, stream);
    k_wt<<<384, 256, 0, stream>>>(W1, W2, Wt1, Wt2);
    k_deg<<<nbE, 256, 0, stream>>>(erow, deg);
    k_dis<<<nbN, 256, 0, stream>>>(deg, dis);
    k_scan1<<<nbS, 256, 0, stream>>>(deg, bsum);
    k_scan2<<<1, 128, 0, stream>>>(bsum, nbS);
    k_scan3<<<nbS, 256, 0, stream>>>(deg, bsum, row_ptr);
    hipMemcpyAsync(cursor, row_ptr, (size_t)NN * 4, hipMemcpyDeviceToDevice, stream);
    k_fill<<<nbE, 256, 0, stream>>>(erow, ecol, dis, cursor, ed);

    // ---- layer 1
    k_mm<128, float><<<g1, 256, 0, stream>>>(x, Wt1, Y);
    k_prop<128><<<pb, 256, 0, stream>>>(row_ptr, ed, Y3, Y2, nullptr,
                                        nullptr, 2.f, 0.f, 0, 0, Y2, nullptr);
    k_prop<128><<<pb, 256, 0, stream>>>(row_ptr, ed, Y2, Y1, Y3,
                                        nullptr, 2.f, -1.f, 0, 0, Y1, nullptr);
    k_prop<128><<<pb, 256, 0, stream>>>(row_ptr, ed, Y1, Y0, Y2,
                                        b1, 1.f, -1.f, 1, 0, Y0, nullptr);

    // ---- layer 2
    k_mm<64, __half><<<g2, 256, 0, stream>>>(Y0, Wt2, Z0);
    k_prop<64><<<pb, 256, 0, stream>>>(row_ptr, ed, Z3, Z2, nullptr,
                                       nullptr, 2.f, 0.f, 0, 0, Z2, nullptr);
    k_prop<64><<<pb, 256, 0, stream>>>(row_ptr, ed, Z2, Z1, Z3,
                                       nullptr, 2.f, -1.f, 0, 0, Z1, nullptr);
    k_prop<64><<<pb, 256, 0, stream>>>(row_ptr, ed, Z1, Z0, Z2,
                                       b2, 1.f, -1.f, 0, 1, nullptr, out);
}

// Round 5
// 987.280 us; speedup vs baseline: 2.0654x; 1.0863x over previous
//
#include <hip/hip_runtime.h>
#include <hip/hip_bf16.h>
#include <hip/hip_fp16.h>

// ChebNet: N=100000 nodes, E=3.2M edges, K=4, 128 -> 128(relu) -> 64 -> log_softmax
// Clenshaw form: sum_k T_k(L) x @ W_k == Clenshaw(L, y_k), y_k = x @ W_k.
// R5: CSR fill rebuilt as bucketed counting sort (R4 showed k_fill 170us with 8x
//     write amplification: 200MB WRITE_SIZE for a 25.6MB array). Bucket = row>>7;
//     staging writes are per-bucket runs (L2-coalesced); final placement is
//     LDS-cursor scatter inside a 32KB L2-resident window.

#define NN 100000
#define NE 3200000
#define NB 782          // ceil(NN/128) buckets of 128 rows

using half8 = __attribute__((ext_vector_type(8))) _Float16;
using floatx4 = __attribute__((ext_vector_type(4))) float;

// ---------------------------------------------------------------- degree / weights
__global__ void k_deg(const int* __restrict__ row, int* __restrict__ deg) {
    int e = blockIdx.x * blockDim.x + threadIdx.x;
    if (e < NE) atomicAdd(&deg[row[e]], 1);
}

__global__ void k_dis(const int* __restrict__ deg, float* __restrict__ dis) {
    int i = blockIdx.x * blockDim.x + threadIdx.x;
    if (i < NN) {
        int d = deg[i];
        dis[i] = (d > 0) ? rsqrtf((float)d) : 0.0f;
    }
}

// ---------------------------------------------------------------- 3-phase exclusive scan (row_ptr)
__global__ void k_scan1(const int* __restrict__ deg, int* __restrict__ bsum) {
    __shared__ int sm[256];
    int t = threadIdx.x, b = blockIdx.x;
    int base = b * 1024 + t * 4;
    int s = 0;
    if (base + 3 < NN) {
        int4 q = *(const int4*)(deg + base);
        s = q.x + q.y + q.z + q.w;
    } else {
        for (int j = 0; j < 4; ++j) { int i = base + j; if (i < NN) s += deg[i]; }
    }
    sm[t] = s; __syncthreads();
    for (int st = 128; st > 0; st >>= 1) {
        if (t < st) sm[t] += sm[t + st];
        __syncthreads();
    }
    if (t == 0) bsum[b] = sm[0];
}

__global__ void k_scan2(int* __restrict__ bsum, int nb) {
    __shared__ int sm[128];
    int t = threadIdx.x;
    int v = (t < nb) ? bsum[t] : 0;
    sm[t] = v; __syncthreads();
    for (int st = 1; st < 128; st <<= 1) {
        int a = (t >= st) ? sm[t - st] : 0;
        __syncthreads();
        sm[t] += a;
        __syncthreads();
    }
    if (t < nb) bsum[t] = (t == 0) ? 0 : sm[t - 1];  // exclusive
}

__global__ void k_scan3(const int* __restrict__ deg, const int* __restrict__ bsum,
                        int* __restrict__ row_ptr) {
    __shared__ int sm[256];
    int t = threadIdx.x, b = blockIdx.x;
    int base = b * 1024 + t * 4;
    int v0 = 0, v1 = 0, v2 = 0, v3 = 0;
    if (base + 3 < NN) {
        int4 q = *(const int4*)(deg + base);
        v0 = q.x; v1 = q.y; v2 = q.z; v3 = q.w;
    } else {
        if (base     < NN) v0 = deg[base];
        if (base + 1 < NN) v1 = deg[base + 1];
        if (base + 2 < NN) v2 = deg[base + 2];
        if (base + 3 < NN) v3 = deg[base + 3];
    }
    int ts = v0 + v1 + v2 + v3;
    sm[t] = ts; __syncthreads();
    for (int st = 1; st < 256; st <<= 1) {
        int a = (t >= st) ? sm[t - st] : 0;
        __syncthreads();
        sm[t] += a;
        __syncthreads();
    }
    int ex = ((t == 0) ? 0 : sm[t - 1]) + bsum[b];
    if (base     < NN) row_ptr[base]     = ex;
    if (base + 1 < NN) row_ptr[base + 1] = ex + v0;
    if (base + 2 < NN) row_ptr[base + 2] = ex + v0 + v1;
    if (base + 3 < NN) row_ptr[base + 3] = ex + v0 + v1 + v2;
    if (b == 0 && t == 0) row_ptr[NN] = NE;
}

// ---------------------------------------------------------------- bucketed CSR build
__global__ void k_binit(const int* __restrict__ row_ptr, int* __restrict__ bcur) {
    int b = blockIdx.x * 256 + threadIdx.x;
    if (b < NB) bcur[b] = row_ptr[b * 128];
}

// pass 1: bucket edges into staging S (packed r_local<<17|c), per-bucket runs
__global__ __launch_bounds__(256) void k_bin(const int* __restrict__ erow,
                                             const int* __restrict__ ecol,
                                             int* __restrict__ bcur,
                                             unsigned int* __restrict__ S) {
    __shared__ int hist[NB];
    __shared__ int base[NB];
    __shared__ int cnt[NB];
    const int t = threadIdx.x;
    const int e0 = blockIdx.x * 8192 + t * 32;

    for (int b = t; b < NB; b += 256) { hist[b] = 0; cnt[b] = 0; }
    __syncthreads();

#pragma unroll
    for (int j = 0; j < 8; ++j) {
        int idx = e0 + j * 4;
        if (idx < NE) {
            int4 r4 = *(const int4*)(erow + idx);
            atomicAdd(&hist[r4.x >> 7], 1);
            atomicAdd(&hist[r4.y >> 7], 1);
            atomicAdd(&hist[r4.z >> 7], 1);
            atomicAdd(&hist[r4.w >> 7], 1);
        }
    }
    __syncthreads();

    for (int b = t; b < NB; b += 256)
        if (hist[b] > 0) base[b] = atomicAdd(&bcur[b], hist[b]);
    __syncthreads();

#pragma unroll
    for (int j = 0; j < 8; ++j) {
        int idx = e0 + j * 4;
        if (idx < NE) {
            int4 r4 = *(const int4*)(erow + idx);
            int4 c4 = *(const int4*)(ecol + idx);
            int rr[4] = {r4.x, r4.y, r4.z, r4.w};
            int cc[4] = {c4.x, c4.y, c4.z, c4.w};
#pragma unroll
            for (int q = 0; q < 4; ++q) {
                int b = rr[q] >> 7;
                int off = atomicAdd(&cnt[b], 1);
                S[base[b] + off] = ((unsigned)(rr[q] & 127) << 17) | (unsigned)cc[q];
            }
        }
    }
}

// pass 2: within-bucket placement via LDS cursors; compute edge weight
__global__ __launch_bounds__(256) void k_place(const int* __restrict__ row_ptr,
                                               const float* __restrict__ dis,
                                               const unsigned int* __restrict__ S,
                                               int2* __restrict__ ed) {
    __shared__ int cur[128];
    __shared__ float disr[128];
    const int b = blockIdx.x;
    const int t = threadIdx.x;
    const int r0 = b * 128;
    const int rows = (r0 + 128 <= NN) ? 128 : (NN - r0);
    if (t < rows) {
        cur[t] = row_ptr[r0 + t];
        disr[t] = dis[r0 + t];
    }
    __syncthreads();
    const int s = row_ptr[r0];
    const int e = row_ptr[r0 + rows];
    for (int i = s + t; i < e; i += 256) {
        unsigned v = S[i];
        int c = v & 131071;
        int rl = v >> 17;
        float wv = -disr[rl] * dis[c];
        int pos = atomicAdd(&cur[rl], 1);
        ed[pos] = make_int2(c, __float_as_int(wv));
    }
}

// ---------------------------------------------------------------- W transpose -> fp16 [N][K]
__global__ void k_wt(const float* __restrict__ W1, const float* __restrict__ W2,
                     __half* __restrict__ Wt1, __half* __restrict__ Wt2) {
    int tid = blockIdx.x * 256 + threadIdx.x;
    if (tid < 512 * 128) {
        int n = tid >> 7, k = tid & 127;
        Wt1[tid] = __float2half_rn(W1[(((n >> 7) * 128) + k) * 128 + (n & 127)]);
    } else {
        int t2 = tid - 512 * 128;
        if (t2 < 256 * 128) {
            int n = t2 >> 7, k = t2 & 127;
            Wt2[t2] = __float2half_rn(W2[(((n >> 6) * 128) + k) * 64 + (n & 63)]);
        }
    }
}

// ---------------------------------------------------------------- MFMA GEMM  Y = X @ Wt^T
template <int OUTC, typename TX>
__global__ __launch_bounds__(256) void k_mm(const TX* __restrict__ X,
                                            const __half* __restrict__ Wt,
                                            __half* __restrict__ Y) {
    __shared__ __half As[128 * 136];
    const int t = threadIdx.x;
    const int lane = t & 63;
    const int w = t >> 6;
    const int r0 = blockIdx.x * 128;
    const int n0 = blockIdx.y * 128;

    if constexpr (sizeof(TX) == 4) {
#pragma unroll
        for (int i = 0; i < 16; ++i) {
            int v = t + i * 256;
            int row = v >> 5, c4 = v & 31;
            float4 xv = make_float4(0.f, 0.f, 0.f, 0.f);
            if (r0 + row < NN) xv = *(const float4*)((const float*)X + (size_t)(r0 + row) * 128 + c4 * 4);
            __half2* p = (__half2*)(As + row * 136 + c4 * 4);
            p[0] = __float22half2_rn(make_float2(xv.x, xv.y));
            p[1] = __float22half2_rn(make_float2(xv.z, xv.w));
        }
    } else {
#pragma unroll
        for (int i = 0; i < 8; ++i) {
            int v = t + i * 256;
            int row = v >> 4, c8 = v & 15;
            uint4 xv = make_uint4(0, 0, 0, 0);
            if (r0 + row < NN) xv = *(const uint4*)((const __half*)X + (size_t)(r0 + row) * 128 + c8 * 8);
            *(uint4*)(As + row * 136 + c8 * 8) = xv;
        }
    }
    __syncthreads();

    const int m = lane & 15, quad = lane >> 4;
    floatx4 acc[2][8] = {};
    const __half* wb = Wt + (size_t)(n0 + m) * 128 + quad * 8;
    const __half* ab = As + (w * 32 + m) * 136 + quad * 8;

#pragma unroll
    for (int ks = 0; ks < 4; ++ks) {
        half8 a0 = *(const half8*)(ab + ks * 32);
        half8 a1 = *(const half8*)(ab + 16 * 136 + ks * 32);
#pragma unroll
        for (int nt = 0; nt < 8; ++nt) {
            half8 b = *(const half8*)(wb + (size_t)nt * 16 * 128 + ks * 32);
            acc[0][nt] = __builtin_amdgcn_mfma_f32_16x16x32_f16(a0, b, acc[0][nt], 0, 0, 0);
            acc[1][nt] = __builtin_amdgcn_mfma_f32_16x16x32_f16(a1, b, acc[1][nt], 0, 0, 0);
        }
    }

    __syncthreads();
#pragma unroll
    for (int mt = 0; mt < 2; ++mt)
#pragma unroll
        for (int nt = 0; nt < 8; ++nt)
#pragma unroll
            for (int rg = 0; rg < 4; ++rg)
                As[(w * 32 + mt * 16 + quad * 4 + rg) * 136 + nt * 16 + m] =
                    __float2half_rn(acc[mt][nt][rg]);
    __syncthreads();

#pragma unroll
    for (int i = 0; i < 8; ++i) {
        int v = t + i * 256;
        int row = v >> 4, c8 = v & 15;
        int node = r0 + row;
        if (node < NN) {
            uint4 val = *(const uint4*)(As + row * 136 + c8 * 8);
            int ng = n0 + c8 * 8;
            __half* dst;
            if (OUTC == 128) dst = Y + ((size_t)(ng >> 7) * NN + node) * 128 + (ng & 127);
            else             dst = Y + ((size_t)(ng >> 6) * NN + node) * 64 + (ng & 63);
            *(uint4*)dst = val;
        }
    }
}

// ---------------------------------------------------------------- propagation (SpMM, multi-edge wave)
template <int C>
__global__ __launch_bounds__(256) void k_prop(const int* __restrict__ rp,
                                              const int2* __restrict__ ed,
                                              const __half* __restrict__ src,
                                              const __half* __restrict__ A,
                                              const __half* __restrict__ B,
                                              const float* __restrict__ bias,
                                              float scale, float betaB, int do_relu,
                                              int do_lsm,
                                              __half* __restrict__ dsth,
                                              float* __restrict__ dstf) {
    constexpr int LPE = C / 8;     // lanes per edge (half8 each)
    constexpr int EG = 64 / LPE;   // concurrent edges per wave
    const int wid = threadIdx.x >> 6;
    const int lane = threadIdx.x & 63;
    const int r = blockIdx.x * 4 + wid;
    if (r >= NN) return;
    const int e0 = rp[r], e1 = rp[r + 1];
    const int eg = lane / LPE, li = lane % LPE;

    float acc[8] = {};
    int e = e0 + eg;
    int2 el0 = (e < e1) ? ed[e] : make_int2(0, 0);
    int2 el1 = (e + EG < e1) ? ed[e + EG] : make_int2(0, 0);
    const int nit2 = (e1 - e0 + 2 * EG - 1) / (2 * EG);   // wave-uniform
    for (int it = 0; it < nit2; ++it) {
        half8 v0 = *(const half8*)(src + (size_t)el0.x * C + li * 8);
        half8 v1 = *(const half8*)(src + (size_t)el1.x * C + li * 8);
        int en0 = e + 2 * EG, en1 = e + 3 * EG;
        int2 p0 = (en0 < e1) ? ed[en0] : make_int2(0, 0);
        int2 p1 = (en1 < e1) ? ed[en1] : make_int2(0, 0);
        float w0 = __int_as_float(el0.y);
        float w1 = __int_as_float(el1.y);
#pragma unroll
        for (int j = 0; j < 8; ++j)
            acc[j] = fmaf(w0, (float)v0[j], fmaf(w1, (float)v1[j], acc[j]));
        e = en0; el0 = p0; el1 = p1;
    }

#pragma unroll
    for (int msk = LPE; msk < 64; msk <<= 1)
#pragma unroll
        for (int j = 0; j < 8; ++j)
            acc[j] += __shfl_xor(acc[j], msk);

    if (eg == 0) {
        size_t o = (size_t)r * C + li * 8;
        float res[8];
        half8 av = *(const half8*)(A + o);
#pragma unroll
        for (int j = 0; j < 8; ++j) res[j] = scale * acc[j] + (float)av[j];
        if (B) {
            half8 bv = *(const half8*)(B + o);
#pragma unroll
            for (int j = 0; j < 8; ++j) res[j] += betaB * (float)bv[j];
        }
        if (bias) {
            float4 b0 = *(const float4*)(bias + li * 8);
            float4 b1 = *(const float4*)(bias + li * 8 + 4);
            res[0] += b0.x; res[1] += b0.y; res[2] += b0.z; res[3] += b0.w;
            res[4] += b1.x; res[5] += b1.y; res[6] += b1.z; res[7] += b1.w;
        }
        if (do_relu)
#pragma unroll
            for (int j = 0; j < 8; ++j) res[j] = fmaxf(res[j], 0.f);
        if (do_lsm) {
            float mx = res[0];
#pragma unroll
            for (int j = 1; j < 8; ++j) mx = fmaxf(mx, res[j]);
            for (int s = 1; s < LPE; s <<= 1) mx = fmaxf(mx, __shfl_xor(mx, s));
            float sum = 0.f;
#pragma unroll
            for (int j = 0; j < 8; ++j) sum += expf(res[j] - mx);
            for (int s = 1; s < LPE; s <<= 1) sum += __shfl_xor(sum, s);
            float lg = mx + logf(sum);
#pragma unroll
            for (int j = 0; j < 8; ++j) res[j] -= lg;
        }
        if (dsth) {
            half8 hv;
#pragma unroll
            for (int j = 0; j < 8; ++j) hv[j] = (_Float16)res[j];
            *(half8*)(dsth + o) = hv;
        }
        if (dstf) {
            *(float4*)(dstf + o) = make_float4(res[0], res[1], res[2], res[3]);
            *(float4*)(dstf + o + 4) = make_float4(res[4], res[5], res[6], res[7]);
        }
    }
}

// ---------------------------------------------------------------- host launch
extern "C" void kernel_launch(void* const* d_in, const int* in_sizes, int n_in,
                              void* d_out, int out_size, void* d_ws, size_t ws_size,
                              hipStream_t stream) {
    const float* x  = (const float*)d_in[0];   // [NN,128]
    const float* W1 = (const float*)d_in[1];   // [4,128,128]
    const float* b1 = (const float*)d_in[2];   // [128]
    const float* W2 = (const float*)d_in[3];   // [4,128,64]
    const float* b2 = (const float*)d_in[4];   // [64]
    const int* ei   = (const int*)d_in[5];     // [2,NE] int
    const int* erow = ei;
    const int* ecol = ei + NE;
    float* out = (float*)d_out;                // [NN,64]

    char* w = (char*)d_ws;
    size_t off = 0;
    auto alloc = [&](size_t bytes) {
        size_t o = off;
        off += (bytes + 255) & ~(size_t)255;
        return o;
    };
    int*   deg     = (int*)(w + alloc((size_t)NN * 4));
    float* dis     = (float*)(w + alloc((size_t)NN * 4));
    int*   row_ptr = (int*)(w + alloc((size_t)(NN + 1) * 4));
    int*   bcur    = (int*)(w + alloc((size_t)NB * 4));
    int*   bsum    = (int*)(w + alloc(256 * 4));
    __half* Wt1    = (__half*)(w + alloc((size_t)512 * 128 * 2));
    __half* Wt2    = (__half*)(w + alloc((size_t)256 * 128 * 2));
    unsigned int* S = (unsigned int*)(w + alloc((size_t)NE * 4));
    int2*  ed      = (int2*)(w + alloc((size_t)NE * 8));
    __half* Y      = (__half*)(w + alloc((size_t)4 * NN * 128 * 2));  // Y0..Y3 fp16
    __half* Y0 = Y;
    __half* Y1 = Y + (size_t)1 * NN * 128;
    __half* Y2 = Y + (size_t)2 * NN * 128;
    __half* Y3 = Y + (size_t)3 * NN * 128;
    __half* Z0 = Y1;
    __half* Z1 = Y1 + (size_t)1 * NN * 64;
    __half* Z2 = Y1 + (size_t)2 * NN * 64;
    __half* Z3 = Y1 + (size_t)3 * NN * 64;

    const int nbE = (NE + 255) / 256;
    const int nbN = (NN + 255) / 256;
    const int nbS = (NN + 1023) / 1024;
    const int pb  = (NN + 3) / 4;
    const dim3 g1((NN + 127) / 128, 4);
    const dim3 g2((NN + 127) / 128, 2);

    // ---- graph weights -> CSR (bucketed counting sort)
    hipMemsetAsync(deg, 0, (size_t)NN * 4, stream);
    k_wt<<<384, 256, 0, stream>>>(W1, W2, Wt1, Wt2);
    k_deg<<<nbE, 256, 0, stream>>>(erow, deg);
    k_dis<<<nbN, 256, 0, stream>>>(deg, dis);
    k_scan1<<<nbS, 256, 0, stream>>>(deg, bsum);
    k_scan2<<<1, 128, 0, stream>>>(bsum, nbS);
    k_scan3<<<nbS, 256, 0, stream>>>(deg, bsum, row_ptr);
    k_binit<<<(NB + 255) / 256, 256, 0, stream>>>(row_ptr, bcur);
    k_bin<<<(NE + 8191) / 8192, 256, 0, stream>>>(erow, ecol, bcur, S);
    k_place<<<NB, 256, 0, stream>>>(row_ptr, dis, S, ed);

    // ---- layer 1
    k_mm<128, float><<<g1, 256, 0, stream>>>(x, Wt1, Y);
    k_prop<128><<<pb, 256, 0, stream>>>(row_ptr, ed, Y3, Y2, nullptr,
                                        nullptr, 2.f, 0.f, 0, 0, Y2, nullptr);
    k_prop<128><<<pb, 256, 0, stream>>>(row_ptr, ed, Y2, Y1, Y3,
                                        nullptr, 2.f, -1.f, 0, 0, Y1, nullptr);
    k_prop<128><<<pb, 256, 0, stream>>>(row_ptr, ed, Y1, Y0, Y2,
                                        b1, 1.f, -1.f, 1, 0, Y0, nullptr);

    // ---- layer 2
    k_mm<64, __half><<<g2, 256, 0, stream>>>(Y0, Wt2, Z0);
    k_prop<64><<<pb, 256, 0, stream>>>(row_ptr, ed, Z3, Z2, nullptr,
                                       nullptr, 2.f, 0.f, 0, 0, Z2, nullptr);
    k_prop<64><<<pb, 256, 0, stream>>>(row_ptr, ed, Z2, Z1, Z3,
                                       nullptr, 2.f, -1.f, 0, 0, Z1, nullptr);
    k_prop<64><<<pb, 256, 0, stream>>>(row_ptr, ed, Z1, Z0, Z2,
                                       b2, 1.f, -1.f, 0, 1, nullptr, out);
}

// Round 6
// 871.831 us; speedup vs baseline: 2.3389x; 1.1324x over previous
//
#include <hip/hip_runtime.h>
#include <hip/hip_bf16.h>
#include <hip/hip_fp16.h>

// ChebNet: N=100000 nodes, E=3.2M edges, K=4, 128 -> 128(relu) -> 64 -> log_softmax
// Clenshaw form: sum_k T_k(L) x @ W_k == Clenshaw(L, y_k), y_k = x @ W_k.
// R6: degree/scan path rebuilt bucket-local (R5 showed k_deg 129us: 3.2M global
//     atomics -> 100MB write traffic on a 400KB array). Bucket counts via LDS
//     histograms + ~300k bucket atomics; per-row degree, row_ptr and dis are
//     computed inside each bucket's contiguous staging run. No global per-row
//     atomics anywhere in the build.

#define NN 100000
#define NE 3200000
#define NB 782          // ceil(NN/128) buckets of 128 rows

using half8 = __attribute__((ext_vector_type(8))) _Float16;
using floatx4 = __attribute__((ext_vector_type(4))) float;

// ---------------------------------------------------------------- pass 1: bucket counts
__global__ __launch_bounds__(256) void k_bcount(const int* __restrict__ erow,
                                                int* __restrict__ bcnt) {
    __shared__ int hist[NB];
    const int t = threadIdx.x;
    const int e0 = blockIdx.x * 8192 + t * 32;
    for (int b = t; b < NB; b += 256) hist[b] = 0;
    __syncthreads();
#pragma unroll
    for (int j = 0; j < 8; ++j) {
        int idx = e0 + j * 4;
        if (idx < NE) {
            int4 r4 = *(const int4*)(erow + idx);
            atomicAdd(&hist[r4.x >> 7], 1);
            atomicAdd(&hist[r4.y >> 7], 1);
            atomicAdd(&hist[r4.z >> 7], 1);
            atomicAdd(&hist[r4.w >> 7], 1);
        }
    }
    __syncthreads();
    for (int b = t; b < NB; b += 256)
        if (hist[b] > 0) atomicAdd(&bcnt[b], hist[b]);
}

// ---------------------------------------------------------------- scan bucket counts -> bbase, bcur
__global__ __launch_bounds__(256) void k_bscan(const int* __restrict__ bcnt,
                                               int* __restrict__ bbase,
                                               int* __restrict__ bcur) {
    __shared__ int sm[256];
    const int t = threadIdx.x;
    int v[4];
    int s = 0;
#pragma unroll
    for (int j = 0; j < 4; ++j) {
        int idx = t * 4 + j;
        v[j] = (idx < NB) ? bcnt[idx] : 0;
        s += v[j];
    }
    sm[t] = s; __syncthreads();
    for (int st = 1; st < 256; st <<= 1) {
        int a = (t >= st) ? sm[t - st] : 0;
        __syncthreads();
        sm[t] += a;
        __syncthreads();
    }
    int ex = (t == 0) ? 0 : sm[t - 1];
#pragma unroll
    for (int j = 0; j < 4; ++j) {
        int idx = t * 4 + j;
        if (idx < NB) { bbase[idx] = ex; bcur[idx] = ex; }
        ex += v[j];
    }
    if (t == 255) bbase[NB] = NE;
}

// ---------------------------------------------------------------- pass 2: bucket edges into staging S
// packed r_local<<17 | c ; per-bucket contiguous runs (aligned with final CSR layout)
__global__ __launch_bounds__(256) void k_bin(const int* __restrict__ erow,
                                             const int* __restrict__ ecol,
                                             int* __restrict__ bcur,
                                             unsigned int* __restrict__ S) {
    __shared__ int hist[NB];
    __shared__ int base[NB];
    __shared__ int cnt[NB];
    const int t = threadIdx.x;
    const int e0 = blockIdx.x * 8192 + t * 32;

    for (int b = t; b < NB; b += 256) { hist[b] = 0; cnt[b] = 0; }
    __syncthreads();

#pragma unroll
    for (int j = 0; j < 8; ++j) {
        int idx = e0 + j * 4;
        if (idx < NE) {
            int4 r4 = *(const int4*)(erow + idx);
            atomicAdd(&hist[r4.x >> 7], 1);
            atomicAdd(&hist[r4.y >> 7], 1);
            atomicAdd(&hist[r4.z >> 7], 1);
            atomicAdd(&hist[r4.w >> 7], 1);
        }
    }
    __syncthreads();

    for (int b = t; b < NB; b += 256)
        if (hist[b] > 0) base[b] = atomicAdd(&bcur[b], hist[b]);
    __syncthreads();

#pragma unroll
    for (int j = 0; j < 8; ++j) {
        int idx = e0 + j * 4;
        if (idx < NE) {
            int4 r4 = *(const int4*)(erow + idx);
            int4 c4 = *(const int4*)(ecol + idx);
            int rr[4] = {r4.x, r4.y, r4.z, r4.w};
            int cc[4] = {c4.x, c4.y, c4.z, c4.w};
#pragma unroll
            for (int q = 0; q < 4; ++q) {
                int b = rr[q] >> 7;
                int off = atomicAdd(&cnt[b], 1);
                S[base[b] + off] = ((unsigned)(rr[q] & 127) << 17) | (unsigned)cc[q];
            }
        }
    }
}

// ---------------------------------------------------------------- per-bucket row_ptr + dis
__global__ __launch_bounds__(256) void k_rowptr(const int* __restrict__ bbase,
                                                const unsigned int* __restrict__ S,
                                                int* __restrict__ row_ptr,
                                                float* __restrict__ dis) {
    __shared__ int hist[128];
    __shared__ int sc[128];
    const int b = blockIdx.x;
    const int t = threadIdx.x;
    const int r0 = b * 128;
    const int rows = (r0 + 128 <= NN) ? 128 : (NN - r0);
    if (t < 128) hist[t] = 0;
    __syncthreads();
    const int s = bbase[b];
    const int e = bbase[b + 1];
    for (int i = s + t; i < e; i += 256)
        atomicAdd(&hist[S[i] >> 17], 1);
    __syncthreads();
    if (t < 128) sc[t] = hist[t];
    __syncthreads();
    for (int st = 1; st < 128; st <<= 1) {
        int a = (t >= st && t < 128) ? sc[t - st] : 0;
        __syncthreads();
        if (t < 128) sc[t] += a;
        __syncthreads();
    }
    if (t < rows) {
        row_ptr[r0 + t] = s + ((t == 0) ? 0 : sc[t - 1]);
        int d = hist[t];
        dis[r0 + t] = (d > 0) ? rsqrtf((float)d) : 0.0f;
    }
    if (b == 0 && t == 0) row_ptr[NN] = NE;
}

// ---------------------------------------------------------------- pass 3: within-bucket placement
__global__ __launch_bounds__(256) void k_place(const int* __restrict__ row_ptr,
                                               const float* __restrict__ dis,
                                               const unsigned int* __restrict__ S,
                                               int2* __restrict__ ed) {
    __shared__ int cur[128];
    __shared__ float disr[128];
    const int b = blockIdx.x;
    const int t = threadIdx.x;
    const int r0 = b * 128;
    const int rows = (r0 + 128 <= NN) ? 128 : (NN - r0);
    if (t < rows) {
        cur[t] = row_ptr[r0 + t];
        disr[t] = dis[r0 + t];
    }
    __syncthreads();
    const int s = row_ptr[r0];
    const int e = row_ptr[r0 + rows];
    for (int i = s + t; i < e; i += 256) {
        unsigned v = S[i];
        int c = v & 131071;
        int rl = v >> 17;
        float wv = -disr[rl] * dis[c];
        int pos = atomicAdd(&cur[rl], 1);
        ed[pos] = make_int2(c, __float_as_int(wv));
    }
}

// ---------------------------------------------------------------- W transpose -> fp16 [N][K]
__global__ void k_wt(const float* __restrict__ W1, const float* __restrict__ W2,
                     __half* __restrict__ Wt1, __half* __restrict__ Wt2) {
    int tid = blockIdx.x * 256 + threadIdx.x;
    if (tid < 512 * 128) {
        int n = tid >> 7, k = tid & 127;
        Wt1[tid] = __float2half_rn(W1[(((n >> 7) * 128) + k) * 128 + (n & 127)]);
    } else {
        int t2 = tid - 512 * 128;
        if (t2 < 256 * 128) {
            int n = t2 >> 7, k = t2 & 127;
            Wt2[t2] = __float2half_rn(W2[(((n >> 6) * 128) + k) * 64 + (n & 63)]);
        }
    }
}

// ---------------------------------------------------------------- MFMA GEMM  Y = X @ Wt^T
template <int OUTC, typename TX>
__global__ __launch_bounds__(256) void k_mm(const TX* __restrict__ X,
                                            const __half* __restrict__ Wt,
                                            __half* __restrict__ Y) {
    __shared__ __half As[128 * 136];
    const int t = threadIdx.x;
    const int lane = t & 63;
    const int w = t >> 6;
    const int r0 = blockIdx.x * 128;
    const int n0 = blockIdx.y * 128;

    if constexpr (sizeof(TX) == 4) {
#pragma unroll
        for (int i = 0; i < 16; ++i) {
            int v = t + i * 256;
            int row = v >> 5, c4 = v & 31;
            float4 xv = make_float4(0.f, 0.f, 0.f, 0.f);
            if (r0 + row < NN) xv = *(const float4*)((const float*)X + (size_t)(r0 + row) * 128 + c4 * 4);
            __half2* p = (__half2*)(As + row * 136 + c4 * 4);
            p[0] = __float22half2_rn(make_float2(xv.x, xv.y));
            p[1] = __float22half2_rn(make_float2(xv.z, xv.w));
        }
    } else {
#pragma unroll
        for (int i = 0; i < 8; ++i) {
            int v = t + i * 256;
            int row = v >> 4, c8 = v & 15;
            uint4 xv = make_uint4(0, 0, 0, 0);
            if (r0 + row < NN) xv = *(const uint4*)((const __half*)X + (size_t)(r0 + row) * 128 + c8 * 8);
            *(uint4*)(As + row * 136 + c8 * 8) = xv;
        }
    }
    __syncthreads();

    const int m = lane & 15, quad = lane >> 4;
    floatx4 acc[2][8] = {};
    const __half* wb = Wt + (size_t)(n0 + m) * 128 + quad * 8;
    const __half* ab = As + (w * 32 + m) * 136 + quad * 8;

#pragma unroll
    for (int ks = 0; ks < 4; ++ks) {
        half8 a0 = *(const half8*)(ab + ks * 32);
        half8 a1 = *(const half8*)(ab + 16 * 136 + ks * 32);
#pragma unroll
        for (int nt = 0; nt < 8; ++nt) {
            half8 b = *(const half8*)(wb + (size_t)nt * 16 * 128 + ks * 32);
            acc[0][nt] = __builtin_amdgcn_mfma_f32_16x16x32_f16(a0, b, acc[0][nt], 0, 0, 0);
            acc[1][nt] = __builtin_amdgcn_mfma_f32_16x16x32_f16(a1, b, acc[1][nt], 0, 0, 0);
        }
    }

    __syncthreads();
#pragma unroll
    for (int mt = 0; mt < 2; ++mt)
#pragma unroll
        for (int nt = 0; nt < 8; ++nt)
#pragma unroll
            for (int rg = 0; rg < 4; ++rg)
                As[(w * 32 + mt * 16 + quad * 4 + rg) * 136 + nt * 16 + m] =
                    __float2half_rn(acc[mt][nt][rg]);
    __syncthreads();

#pragma unroll
    for (int i = 0; i < 8; ++i) {
        int v = t + i * 256;
        int row = v >> 4, c8 = v & 15;
        int node = r0 + row;
        if (node < NN) {
            uint4 val = *(const uint4*)(As + row * 136 + c8 * 8);
            int ng = n0 + c8 * 8;
            __half* dst;
            if (OUTC == 128) dst = Y + ((size_t)(ng >> 7) * NN + node) * 128 + (ng & 127);
            else             dst = Y + ((size_t)(ng >> 6) * NN + node) * 64 + (ng & 63);
            *(uint4*)dst = val;
        }
    }
}

// ---------------------------------------------------------------- propagation (SpMM, multi-edge wave)
template <int C>
__global__ __launch_bounds__(256) void k_prop(const int* __restrict__ rp,
                                              const int2* __restrict__ ed,
                                              const __half* __restrict__ src,
                                              const __half* __restrict__ A,
                                              const __half* __restrict__ B,
                                              const float* __restrict__ bias,
                                              float scale, float betaB, int do_relu,
                                              int do_lsm,
                                              __half* __restrict__ dsth,
                                              float* __restrict__ dstf) {
    constexpr int LPE = C / 8;     // lanes per edge (half8 each)
    constexpr int EG = 64 / LPE;   // concurrent edges per wave
    const int wid = threadIdx.x >> 6;
    const int lane = threadIdx.x & 63;
    const int r = blockIdx.x * 4 + wid;
    if (r >= NN) return;
    const int e0 = rp[r], e1 = rp[r + 1];
    const int eg = lane / LPE, li = lane % LPE;

    float acc[8] = {};
    int e = e0 + eg;
    int2 el0 = (e < e1) ? ed[e] : make_int2(0, 0);
    int2 el1 = (e + EG < e1) ? ed[e + EG] : make_int2(0, 0);
    const int nit2 = (e1 - e0 + 2 * EG - 1) / (2 * EG);   // wave-uniform
    for (int it = 0; it < nit2; ++it) {
        half8 v0 = *(const half8*)(src + (size_t)el0.x * C + li * 8);
        half8 v1 = *(const half8*)(src + (size_t)el1.x * C + li * 8);
        int en0 = e + 2 * EG, en1 = e + 3 * EG;
        int2 p0 = (en0 < e1) ? ed[en0] : make_int2(0, 0);
        int2 p1 = (en1 < e1) ? ed[en1] : make_int2(0, 0);
        float w0 = __int_as_float(el0.y);
        float w1 = __int_as_float(el1.y);
#pragma unroll
        for (int j = 0; j < 8; ++j)
            acc[j] = fmaf(w0, (float)v0[j], fmaf(w1, (float)v1[j], acc[j]));
        e = en0; el0 = p0; el1 = p1;
    }

#pragma unroll
    for (int msk = LPE; msk < 64; msk <<= 1)
#pragma unroll
        for (int j = 0; j < 8; ++j)
            acc[j] += __shfl_xor(acc[j], msk);

    if (eg == 0) {
        size_t o = (size_t)r * C + li * 8;
        float res[8];
        half8 av = *(const half8*)(A + o);
#pragma unroll
        for (int j = 0; j < 8; ++j) res[j] = scale * acc[j] + (float)av[j];
        if (B) {
            half8 bv = *(const half8*)(B + o);
#pragma unroll
            for (int j = 0; j < 8; ++j) res[j] += betaB * (float)bv[j];
        }
        if (bias) {
            float4 b0 = *(const float4*)(bias + li * 8);
            float4 b1 = *(const float4*)(bias + li * 8 + 4);
            res[0] += b0.x; res[1] += b0.y; res[2] += b0.z; res[3] += b0.w;
            res[4] += b1.x; res[5] += b1.y; res[6] += b1.z; res[7] += b1.w;
        }
        if (do_relu)
#pragma unroll
            for (int j = 0; j < 8; ++j) res[j] = fmaxf(res[j], 0.f);
        if (do_lsm) {
            float mx = res[0];
#pragma unroll
            for (int j = 1; j < 8; ++j) mx = fmaxf(mx, res[j]);
            for (int s = 1; s < LPE; s <<= 1) mx = fmaxf(mx, __shfl_xor(mx, s));
            float sum = 0.f;
#pragma unroll
            for (int j = 0; j < 8; ++j) sum += expf(res[j] - mx);
            for (int s = 1; s < LPE; s <<= 1) sum += __shfl_xor(sum, s);
            float lg = mx + logf(sum);
#pragma unroll
            for (int j = 0; j < 8; ++j) res[j] -= lg;
        }
        if (dsth) {
            half8 hv;
#pragma unroll
            for (int j = 0; j < 8; ++j) hv[j] = (_Float16)res[j];
            *(half8*)(dsth + o) = hv;
        }
        if (dstf) {
            *(float4*)(dstf + o) = make_float4(res[0], res[1], res[2], res[3]);
            *(float4*)(dstf + o + 4) = make_float4(res[4], res[5], res[6], res[7]);
        }
    }
}

// ---------------------------------------------------------------- host launch
extern "C" void kernel_launch(void* const* d_in, const int* in_sizes, int n_in,
                              void* d_out, int out_size, void* d_ws, size_t ws_size,
                              hipStream_t stream) {
    const float* x  = (const float*)d_in[0];   // [NN,128]
    const float* W1 = (const float*)d_in[1];   // [4,128,128]
    const float* b1 = (const float*)d_in[2];   // [128]
    const float* W2 = (const float*)d_in[3];   // [4,128,64]
    const float* b2 = (const float*)d_in[4];   // [64]
    const int* ei   = (const int*)d_in[5];     // [2,NE] int
    const int* erow = ei;
    const int* ecol = ei + NE;
    float* out = (float*)d_out;                // [NN,64]

    char* w = (char*)d_ws;
    size_t off = 0;
    auto alloc = [&](size_t bytes) {
        size_t o = off;
        off += (bytes + 255) & ~(size_t)255;
        return o;
    };
    float* dis     = (float*)(w + alloc((size_t)NN * 4));
    int*   row_ptr = (int*)(w + alloc((size_t)(NN + 1) * 4));
    int*   bcnt    = (int*)(w + alloc((size_t)NB * 4));
    int*   bbase   = (int*)(w + alloc((size_t)(NB + 1) * 4));
    int*   bcur    = (int*)(w + alloc((size_t)NB * 4));
    __half* Wt1    = (__half*)(w + alloc((size_t)512 * 128 * 2));
    __half* Wt2    = (__half*)(w + alloc((size_t)256 * 128 * 2));
    unsigned int* S = (unsigned int*)(w + alloc((size_t)NE * 4));
    int2*  ed      = (int2*)(w + alloc((size_t)NE * 8));
    __half* Y      = (__half*)(w + alloc((size_t)4 * NN * 128 * 2));  // Y0..Y3 fp16
    __half* Y0 = Y;
    __half* Y1 = Y + (size_t)1 * NN * 128;
    __half* Y2 = Y + (size_t)2 * NN * 128;
    __half* Y3 = Y + (size_t)3 * NN * 128;
    __half* Z0 = Y1;
    __half* Z1 = Y1 + (size_t)1 * NN * 64;
    __half* Z2 = Y1 + (size_t)2 * NN * 64;
    __half* Z3 = Y1 + (size_t)3 * NN * 64;

    const int pb  = (NN + 3) / 4;
    const int ebB = (NE + 8191) / 8192;     // 391 blocks for edge passes
    const dim3 g1((NN + 127) / 128, 4);
    const dim3 g2((NN + 127) / 128, 2);

    // ---- graph build: bucketed counting sort, no global per-row atomics
    hipMemsetAsync(bcnt, 0, (size_t)NB * 4, stream);
    k_wt<<<384, 256, 0, stream>>>(W1, W2, Wt1, Wt2);
    k_bcount<<<ebB, 256, 0, stream>>>(erow, bcnt);
    k_bscan<<<1, 256, 0, stream>>>(bcnt, bbase, bcur);
    k_bin<<<ebB, 256, 0, stream>>>(erow, ecol, bcur, S);
    k_rowptr<<<NB, 256, 0, stream>>>(bbase, S, row_ptr, dis);
    k_place<<<NB, 256, 0, stream>>>(row_ptr, dis, S, ed);

    // ---- layer 1
    k_mm<128, float><<<g1, 256, 0, stream>>>(x, Wt1, Y);
    k_prop<128><<<pb, 256, 0, stream>>>(row_ptr, ed, Y3, Y2, nullptr,
                                        nullptr, 2.f, 0.f, 0, 0, Y2, nullptr);
    k_prop<128><<<pb, 256, 0, stream>>>(row_ptr, ed, Y2, Y1, Y3,
                                        nullptr, 2.f, -1.f, 0, 0, Y1, nullptr);
    k_prop<128><<<pb, 256, 0, stream>>>(row_ptr, ed, Y1, Y0, Y2,
                                        b1, 1.f, -1.f, 1, 0, Y0, nullptr);

    // ---- layer 2
    k_mm<64, __half><<<g2, 256, 0, stream>>>(Y0, Wt2, Z0);
    k_prop<64><<<pb, 256, 0, stream>>>(row_ptr, ed, Z3, Z2, nullptr,
                                       nullptr, 2.f, 0.f, 0, 0, Z2, nullptr);
    k_prop<64><<<pb, 256, 0, stream>>>(row_ptr, ed, Z2, Z1, Z3,
                                       nullptr, 2.f, -1.f, 0, 0, Z1, nullptr);
    k_prop<64><<<pb, 256, 0, stream>>>(row_ptr, ed, Z1, Z0, Z2,
                                       b2, 1.f, -1.f, 0, 1, nullptr, out);
}